// Round 13
// baseline (1898.194 us; speedup 1.0000x reference)
//
#include <hip/hip_runtime.h>
#include <cstdint>

#define Bn 4
#define Nn 16384
#define Mn 512
#define Kn 32

// output offsets (floats)
#define O_SAL 6144
#define O_RC  8192
#define O_AFM 794624

__device__ __forceinline__ unsigned fkey(float f) {
  unsigned b = __float_as_uint(f);
  return (b & 0x80000000u) ? ~b : (b | 0x80000000u);
}

__device__ __forceinline__ unsigned long long dkey(double d) {
  unsigned long long b = (unsigned long long)__double_as_longlong(d);
  return (b & 0x8000000000000000ull) ? ~b : (b | 0x8000000000000000ull);
}

// ---- kernel 0: per-point squared norm (np: materialized square + seq sum, NO FMA) ----
// Also zeroes the 4 fps->knn sync flags (aliased into the gcf region; runs
// before the fused kernel on the same stream each iteration).
__global__ __launch_bounds__(256) void sq_kernel(const float* __restrict__ x,
                                                 float* __restrict__ sqp,
                                                 unsigned long long* __restrict__ flags) {
#pragma clang fp contract(off)
  int i = blockIdx.x * 256 + threadIdx.x;  // < B*N
  if (blockIdx.x == 0 && threadIdx.x < 4) flags[threadIdx.x * 8] = 0ull;
  float4 v = ((const float4*)x)[i];
  float qx = v.x * v.x;
  float qy = v.y * v.y;
  float qz = v.z * v.z;
  sqp[i] = (qx + qy) + qz;
}

// DPP max step: moved = lane-shuffled v (old = self fallback), then max.
// Values are >= 0 here, so either bound_ctrl semantic (old or 0) is safe.
template <int CTRL>
__device__ __forceinline__ float dppmaxf(float v) {
  int m = __builtin_amdgcn_update_dpp(__float_as_int(v), __float_as_int(v),
                                      CTRL, 0xf, 0xf, false);
  return fmaxf(v, __int_as_float(m));
}

// ------------- fused kernel: fps (blocks 0-3) + knn workers (blocks 4-255) -------------
// r12 post-mortem: fusion worked (knn hidden) but fps slowed 884->1297us.
// Mechanism: 512 blocks x 16 waves = 2 blocks/CU -> each fps block SHARED its
// CU with a 16-wave worker block, halving fps VALU issue on a latency-bound
// loop (1.47x observed ~= 2x issue-share). Fix: 256 blocks + 84KB DYNAMIC
// LDS (launch parameter - cannot be DCE'd like r4's dummy array; 2x84KB >
// 160KB) -> hardware-capped 1 block/CU, 256 blocks = 256 CUs, all
// co-resident (handshake deadlock-free), fps on DEDICATED CUs.
// fps path: EXACT r5 code + per-batch chunk counter published every 8 steps
// (t==0, agent-scope RELEASE). Workers: item j=(w-4)+252k -> (m=j>>2,
// b=j&3); tail items (m>=504) map one-per-worker to workers 4..35 ->
// tail ~ one item. Wait: t==0 ACQUIRE spin (s_sleep throttled), barrier.
// knn body at 1024 threads (16 keys/thread): same distance formula/order,
// same radix counts/threshold, same bitonic, same ties -> bit-identical sel.
// Flags alias gcf region (sq zeroes before; group clobbers after).
__global__ __launch_bounds__(1024)
__attribute__((amdgpu_waves_per_eu(4, 4)))
void fused_fps_knn(const float* __restrict__ x, float* __restrict__ node,
                   const float* __restrict__ sqp,
                   const int* __restrict__ rand_idx, int* __restrict__ sel,
                   unsigned long long* __restrict__ flags) {
#pragma clang fp contract(off)
  const int t = threadIdx.x;
  extern __shared__ float lds_force[];  // 84KB dynamic: caps at 1 block/CU
  // fps shared
  __shared__ __align__(16) unsigned long long kkey[2][16];
  // worker shared
  __shared__ unsigned hist[256];
  __shared__ unsigned gsum[16];
  __shared__ unsigned sh_prefix;
  __shared__ int sh_r;
  __shared__ int cnt;
  __shared__ unsigned long long karr[128];
  if (blockIdx.x == 0xFFFFFFFF) lds_force[t] = 0.f;  // dynamic LDS is reserved by launch regardless

  if (blockIdx.x < 4) {
    // ---------------- fps producer (exact r5 structure) ----------------
    const int b = blockIdx.x;
    const float4* xb = (const float4*)(x + (size_t)b * Nn * 4);
    float px[16], py[16], pz[16], mind[16];
    const int base = t * 16;
#pragma unroll
    for (int i = 0; i < 16; ++i) {
      float4 v = xb[base + i];
      px[i] = v.x; py[i] = v.y; pz[i] = v.z;
      mind[i] = 1e10f;
    }
    float cx, cy, cz;
    {
      float4 v = xb[0];
      cx = v.x; cy = v.y; cz = v.z;
      if (t == 0) ((float4*)node)[b * Mn] = v;
    }
    for (int s = 1; s < Mn; ++s) {
      // pass 1: distance + running min (exact np order, no contraction)
#pragma unroll
      for (int i = 0; i < 16; ++i) {
        float dx = px[i] - cx;
        float dy = py[i] - cy;
        float dz = pz[i] - cz;
        float qx = dx * dx;
        float qy = dy * dy;
        float qz = dz * dz;
        float d = (qx + qy) + qz;
        mind[i] = fminf(mind[i], d);
      }
      // pass 2: value max tree
      float a0 = fmaxf(mind[0], mind[1]);
      float a1 = fmaxf(mind[2], mind[3]);
      float a2 = fmaxf(mind[4], mind[5]);
      float a3 = fmaxf(mind[6], mind[7]);
      float a4 = fmaxf(mind[8], mind[9]);
      float a5 = fmaxf(mind[10], mind[11]);
      float a6 = fmaxf(mind[12], mind[13]);
      float a7 = fmaxf(mind[14], mind[15]);
      float b0 = fmaxf(a0, a1);
      float b1 = fmaxf(a2, a3);
      float b2 = fmaxf(a4, a5);
      float b3 = fmaxf(a6, a7);
      float bv = fmaxf(fmaxf(b0, b1), fmaxf(b2, b3));
      // pass 3: lowest matching lane-local index (descending scan)
      int isel = 0;
#pragma unroll
      for (int i = 15; i >= 0; --i)
        if (mind[i] == bv) isel = i;
      // wave reduce: value-only DPP max -> lane 63 -> uniform
      float r = bv;
      r = dppmaxf<0x111>(r);
      r = dppmaxf<0x112>(r);
      r = dppmaxf<0x114>(r);
      r = dppmaxf<0x118>(r);
      r = dppmaxf<0x142>(r);
      r = dppmaxf<0x143>(r);
      float wmax = __int_as_float(__builtin_amdgcn_readlane(__float_as_int(r), 63));
      unsigned long long ball = __ballot(bv == wmax);
      int wl = __ffsll(ball) - 1;
      int widx = __builtin_amdgcn_readlane(base + isel, wl);
      if ((t & 63) == 0) {
        kkey[s & 1][t >> 6] =
            ((unsigned long long)(__float_as_uint(wmax) | 0x80000000u) << 32) |
            (unsigned)(~widx);
      }
      __syncthreads();
      {
        unsigned long long kk = kkey[s & 1][t & 15];
#pragma unroll
        for (int off = 1; off < 16; off <<= 1) {
          unsigned long long ok = __shfl_xor(kk, off, 16);
          kk = ok > kk ? ok : kk;
        }
        int wi = __builtin_amdgcn_readfirstlane((int)(~(unsigned)(kk & 0xFFFFFFFFu)));
        float4 nv = xb[wi];
        cx = nv.x; cy = nv.y; cz = nv.z;
        if (t == 0) ((float4*)node)[b * Mn + s] = nv;
      }
      // publish completed 8-node chunks (release: all prior node stores visible)
      if (((s & 7) == 7) && t == 0) {
        __hip_atomic_store(&flags[b * 8], (unsigned long long)((s + 1) >> 3),
                           __ATOMIC_RELEASE, __HIP_MEMORY_SCOPE_AGENT);
      }
    }
  } else {
    // ---------------- knn workers (1024 threads, 16 keys/thread) ----------------
    const int w = blockIdx.x - 4;
    for (int j = w; j < Bn * Mn; j += 252) {
      const int m = j >> 2;
      const int bb = j & 3;
      // wait for node[bb][m]: chunk (m>>3)+1 published
      if (t == 0) {
        unsigned long long need = (unsigned long long)((m >> 3) + 1);
        while (__hip_atomic_load(&flags[bb * 8], __ATOMIC_ACQUIRE,
                                 __HIP_MEMORY_SCOPE_AGENT) < need)
          __builtin_amdgcn_s_sleep(8);
      }
      __syncthreads();

      const int bm = bb * Mn + m;
      const float4* xb = (const float4*)(x + (size_t)bb * Nn * 4);
      const float* sq_b = sqp + bb * Nn;
      float4 nd = ((const float4*)node)[bm];
      const float nx = nd.x, ny = nd.y, nz = nd.z;
      const float sqmf = (nx * nx + ny * ny) + nz * nz;
      unsigned key[16];
#pragma unroll
      for (int i = 0; i < 16; ++i) {
        int n = t + (i << 10);
        float4 v = xb[n];
        float dot = nx * v.x;
        dot = __builtin_fmaf(ny, v.y, dot);
        dot = __builtin_fmaf(nz, v.z, dot);
        float d2 = (sqmf + sq_b[n]) - 2.0f * dot;
        key[i] = fkey(d2);
      }
      // radix-select rank-95 (byte-wise, 4 passes; same counts/threshold)
      unsigned prefix = 0, pmask = 0;
      int r = 95;
      for (int shift = 24; shift >= 0; shift -= 8) {
        if (t < 256) hist[t] = 0;
        __syncthreads();
#pragma unroll
        for (int i = 0; i < 16; ++i) {
          if ((key[i] & pmask) == prefix)
            atomicAdd(&hist[(key[i] >> shift) & 255], 1u);
        }
        __syncthreads();
        if (t < 16) {
          unsigned ssum = 0;
#pragma unroll
          for (int jj = 0; jj < 16; ++jj) ssum += hist[t * 16 + jj];
          gsum[t] = ssum;
        }
        __syncthreads();
        if (t == 0) {
          int rr = r;
          unsigned g = 0;
          for (unsigned jj = 0; jj < 16; ++jj) {
            int c = (int)gsum[jj];
            if (rr < c) { g = jj; break; }
            rr -= c;
          }
          unsigned bin = g * 16;
          for (unsigned jj = 0; jj < 16; ++jj) {
            int c = (int)hist[g * 16 + jj];
            if (rr < c) { bin = g * 16 + jj; break; }
            rr -= c;
          }
          sh_prefix = prefix | (bin << shift);
          sh_r = rr;
        }
        __syncthreads();
        prefix = sh_prefix;
        r = sh_r;
        pmask |= (0xFFu << shift);
      }
      const unsigned T = prefix;  // collect keys <= T (>=96 candidates; cap 128)
      if (t == 0) cnt = 0;
      __syncthreads();
#pragma unroll
      for (int i = 0; i < 16; ++i) {
        if (key[i] <= T) {
          int pos = atomicAdd(&cnt, 1);
          if (pos < 128) {
            unsigned n = (unsigned)(t + (i << 10));
            karr[pos] = ((unsigned long long)key[i] << 32) | n;
          }
        }
      }
      __syncthreads();
      const int nc = cnt < 128 ? cnt : 128;
      if (t < 128 && t >= nc) karr[t] = ~0ull;
      // 128-wide bitonic sort ascending (identical to standalone version)
      for (int k = 2; k <= 128; k <<= 1) {
        for (int jj = k >> 1; jj > 0; jj >>= 1) {
          __syncthreads();
          if (t < 64) {
            int i = ((t & ~(jj - 1)) << 1) | (t & (jj - 1));
            int ip = i | jj;
            unsigned long long ka = karr[i], kb = karr[ip];
            bool asc = ((i & k) == 0);
            if ((ka > kb) == asc) { karr[i] = kb; karr[ip] = ka; }
          }
        }
      }
      __syncthreads();
      if (t < 32) {
        int ri = rand_idx[t];  // in [0,64)
        sel[bm * 32 + t] = (int)(unsigned)(karr[ri] & 0xFFFFFFFFu);
      }
      __syncthreads();  // protect LDS reuse across items
    }
  }
}

// ---------------- kernel 3: fused group pipeline (r11 version, unchanged) ----------------
__global__ __launch_bounds__(256) void group_kernel(
    const float* __restrict__ x, const float* __restrict__ node,
    const int* __restrict__ sel, const float* __restrict__ w_e1,
    const float* __restrict__ g1, const float* __restrict__ b1,
    const float* __restrict__ w_e2, const float* __restrict__ g2,
    const float* __restrict__ b2, float* __restrict__ out,
    float* __restrict__ gcf) {
#pragma clang fp contract(off)
  const int bm = blockIdx.x;
  const int b = bm >> 9;
  const int m = bm & 511;
  const int t = threadIdx.x;

  __shared__ float cl[32][13];
  __shared__ float h1t[64][36];
  __shared__ float h1p[32][68];
  __shared__ unsigned char nbr[32][8];
  __shared__ double sqs[32];
  __shared__ float part[4][32];
  __shared__ float aws[32];
  __shared__ union U {
    struct {
      unsigned long long keys[32][32];
      float we_a[12][64];
      float we_d[12][64];
      float a1[32][65];
      float cd1[32][65];
    } s;
    float a2[32 * 256];
  } u;

  const float4* xb = (const float4*)(x + (size_t)b * Nn * 4);
  const float4 ndv = ((const float4*)node)[bm];

  if (t < 32) {
    int n = sel[bm * 32 + t];
    float4 v = xb[n];
    float rx = v.x - ndv.x;
    float ry = v.y - ndv.y;
    float rz = v.z - ndv.z;
    float ds = (rx * rx + ry * ry) + rz * rz;
    ds = __fsqrt_rn(ds);
    cl[t][0] = ndv.x; cl[t][1] = ndv.y; cl[t][2] = ndv.z; cl[t][3] = ndv.w;
    cl[t][4] = v.x;   cl[t][5] = v.y;   cl[t][6] = v.z;   cl[t][7] = v.w;
    cl[t][8] = rx;    cl[t][9] = ry;    cl[t][10] = rz;   cl[t][11] = ds;
  }
  for (int i = t; i < 768; i += 256) {
    int row = i >> 6, d = i & 63;
    float wa = w_e1[row * 64 + d];
    float wb = w_e1[(row + 12) * 64 + d];
    u.s.we_a[row][d] = wa;
    u.s.we_d[row][d] = wb - wa;
  }
  __syncthreads();

  for (int i = t; i < 384; i += 256) {
    int c = i >> 5, p = i & 31;
    out[O_RC + (((size_t)(b * 12 + c) * 512) + m) * 32 + p] = cl[p][c];
  }
  if (t < 32) {
    double q[12];
#pragma unroll
    for (int c = 0; c < 12; ++c) {
      double cv = (double)cl[t][c];
      q[c] = cv * cv;
    }
    double s01 = q[0] + q[1];
    double s23 = q[2] + q[3];
    double s45 = q[4] + q[5];
    double s67 = q[6] + q[7];
    double s = (s01 + s23) + (s45 + s67);
    s = s + q[8];
    s = s + q[9];
    s = s + q[10];
    s = s + q[11];
    sqs[t] = s;
  }
  __syncthreads();

  // pairwise d2 (12-d, fp64 order-exact) -> keys
  {
    int p = t >> 3, q0 = (t & 7) << 2;
#pragma unroll
    for (int qq = 0; qq < 4; ++qq) {
      int q = q0 + qq;
      double dot = 0.0;
#pragma unroll
      for (int c = 0; c < 12; ++c)
        dot = dot + (double)cl[p][c] * (double)cl[q][c];
      double d2 = (sqs[p] + sqs[q]) - 2.0 * dot;
      u.s.keys[p][q] = dkey(d2);
    }
  }
  __syncthreads();

  // parallel rank-select top-8 (identical stable lowest-index-ties semantics)
  {
    int p = t >> 3, s8 = t & 7;
    unsigned long long kq0 = u.s.keys[p][s8];
    unsigned long long kq1 = u.s.keys[p][s8 + 8];
    unsigned long long kq2 = u.s.keys[p][s8 + 16];
    unsigned long long kq3 = u.s.keys[p][s8 + 24];
    int r0 = 0, r1 = 0, r2 = 0, r3 = 0;
#pragma unroll
    for (int j = 0; j < 32; ++j) {
      int jj = (j + p) & 31;  // lane-staggered: conflict-free row reads
      unsigned long long kj = u.s.keys[p][jj];
      r0 += (kj < kq0 || (kj == kq0 && jj < s8));
      r1 += (kj < kq1 || (kj == kq1 && jj < s8 + 8));
      r2 += (kj < kq2 || (kj == kq2 && jj < s8 + 16));
      r3 += (kj < kq3 || (kj == kq3 && jj < s8 + 24));
    }
    if (r0 < 8) nbr[p][r0] = (unsigned char)s8;
    if (r1 < 8) nbr[p][r1] = (unsigned char)(s8 + 8);
    if (r2 < 8) nbr[p][r2] = (unsigned char)(s8 + 16);
    if (r3 < 8) nbr[p][r3] = (unsigned char)(s8 + 24);
  }
  {
    int d = t & 63, pg = (t >> 6) << 3;
#pragma unroll
    for (int pp = 0; pp < 8; ++pp) {
      int p = pg + pp;
      float aA = 0.f, aD = 0.f;
#pragma unroll
      for (int c = 0; c < 12; ++c) {
        float xv = cl[p][c];
        aA = fmaf(xv, u.s.we_a[c][d], aA);
        aD = fmaf(xv, u.s.we_d[c][d], aD);
      }
      u.s.a1[p][d] = aA;
      u.s.cd1[p][d] = aD;
    }
  }
  __syncthreads();

  {
    int d = t & 63, pg = (t >> 6) << 3;
    float g1v = g1[d], b1v = b1[d];
#pragma unroll
    for (int pp = 0; pp < 8; ++pp) {
      int p = pg + pp;
      float cd = u.s.cd1[p][d];
      float hm = -1e30f;
#pragma unroll
      for (int k = 0; k < 8; ++k) {
        int j = nbr[p][k];
        float hv = fmaf(g1v, u.s.a1[j][d] + cd, b1v);
        hv = fmaxf(hv, 0.f);
        hm = fmaxf(hm, hv);
      }
      h1t[d][p] = hm;
      h1p[p][d] = hm;
    }
  }
  __syncthreads();

  if (t < 32) {
    double r[8];
#pragma unroll
    for (int j = 0; j < 8; ++j) {
      double hv = (double)h1p[t][j];
      r[j] = hv * hv;
    }
#pragma unroll
    for (int blk = 1; blk < 8; ++blk) {
#pragma unroll
      for (int j = 0; j < 8; ++j) {
        double hv = (double)h1p[t][blk * 8 + j];
        r[j] = r[j] + hv * hv;
      }
    }
    double s01 = r[0] + r[1];
    double s23 = r[2] + r[3];
    double s45 = r[4] + r[5];
    double s67 = r[6] + r[7];
    sqs[t] = (s01 + s23) + (s45 + s67);
  }
  __syncthreads();

  // pairwise d2 over h1 (64-d, fp64, float4-vectorized; same seq order)
  {
    int p = t >> 3, q0 = (t & 7) << 2;
    const float4* rp = (const float4*)&h1p[p][0];
    for (int qq = 0; qq < 4; ++qq) {
      int q = q0 + qq;
      const float4* rq = (const float4*)&h1p[q][0];
      double dot = 0.0;
#pragma unroll
      for (int c4 = 0; c4 < 16; ++c4) {
        float4 av = rp[c4];
        float4 bv = rq[c4];
        dot = dot + (double)av.x * (double)bv.x;
        dot = dot + (double)av.y * (double)bv.y;
        dot = dot + (double)av.z * (double)bv.z;
        dot = dot + (double)av.w * (double)bv.w;
      }
      double d2 = (sqs[p] + sqs[q]) - 2.0 * dot;
      u.s.keys[p][q] = dkey(d2);
    }
  }
  __syncthreads();

  // parallel rank-select top-8 (second neighbor search)
  {
    int p = t >> 3, s8 = t & 7;
    unsigned long long kq0 = u.s.keys[p][s8];
    unsigned long long kq1 = u.s.keys[p][s8 + 8];
    unsigned long long kq2 = u.s.keys[p][s8 + 16];
    unsigned long long kq3 = u.s.keys[p][s8 + 24];
    int r0 = 0, r1 = 0, r2 = 0, r3 = 0;
#pragma unroll
    for (int j = 0; j < 32; ++j) {
      int jj = (j + p) & 31;
      unsigned long long kj = u.s.keys[p][jj];
      r0 += (kj < kq0 || (kj == kq0 && jj < s8));
      r1 += (kj < kq1 || (kj == kq1 && jj < s8 + 8));
      r2 += (kj < kq2 || (kj == kq2 && jj < s8 + 16));
      r3 += (kj < kq3 || (kj == kq3 && jj < s8 + 24));
    }
    if (r0 < 8) nbr[p][r0] = (unsigned char)s8;
    if (r1 < 8) nbr[p][r1] = (unsigned char)(s8 + 8);
    if (r2 < 8) nbr[p][r2] = (unsigned char)(s8 + 16);
    if (r3 < 8) nbr[p][r3] = (unsigned char)(s8 + 24);
  }
  __syncthreads();

  float accD[32];
  float embv[32];
  {
    float accA[32];
#pragma unroll
    for (int p = 0; p < 32; ++p) { accA[p] = 0.f; accD[p] = 0.f; }
    for (int c = 0; c < 64; ++c) {
      float wt = w_e2[c * 256 + t];
      float wb = w_e2[(c + 64) * 256 + t];
      float wd = wb - wt;
      const float4* row = (const float4*)&h1t[c][0];
#pragma unroll
      for (int p4 = 0; p4 < 8; ++p4) {
        float4 hv = row[p4];
        accA[4 * p4 + 0] = fmaf(hv.x, wt, accA[4 * p4 + 0]);
        accA[4 * p4 + 1] = fmaf(hv.y, wt, accA[4 * p4 + 1]);
        accA[4 * p4 + 2] = fmaf(hv.z, wt, accA[4 * p4 + 2]);
        accA[4 * p4 + 3] = fmaf(hv.w, wt, accA[4 * p4 + 3]);
        accD[4 * p4 + 0] = fmaf(hv.x, wd, accD[4 * p4 + 0]);
        accD[4 * p4 + 1] = fmaf(hv.y, wd, accD[4 * p4 + 1]);
        accD[4 * p4 + 2] = fmaf(hv.z, wd, accD[4 * p4 + 2]);
        accD[4 * p4 + 3] = fmaf(hv.w, wd, accD[4 * p4 + 3]);
      }
    }
#pragma unroll
    for (int p = 0; p < 32; ++p) u.a2[p * 256 + t] = accA[p];
  }
  __syncthreads();
  {
    float g2v = g2[t], b2v = b2[t];
#pragma unroll
    for (int p = 0; p < 32; ++p) {
      float cd = accD[p];
      float e = -1e30f;
#pragma unroll
      for (int k = 0; k < 8; ++k) {
        int j = nbr[p][k];
        float hv = fmaf(g2v, u.a2[j * 256 + t] + cd, b2v);
        hv = fmaxf(hv, 0.f);
        e = fmaxf(e, hv);
      }
      embv[p] = e;
    }
  }

#pragma unroll
  for (int p = 0; p < 32; ++p) {
    float v = embv[p];
#pragma unroll
    for (int off = 32; off > 0; off >>= 1) v = fmaxf(v, __shfl_xor(v, off));
    if ((t & 63) == 0) part[t >> 6][p] = v;
  }
  __syncthreads();

  if (t < 32) {
    float x1 = fmaxf(fmaxf(part[0][t], part[1][t]), fmaxf(part[2][t], part[3][t]));
    float mx = x1;
#pragma unroll
    for (int off = 16; off > 0; off >>= 1) mx = fmaxf(mx, __shfl_xor(mx, off));
    float ex = expf(x1 - mx);
    float sm = ex;
#pragma unroll
    for (int off = 16; off > 0; off >>= 1) sm += __shfl_xor(sm, off);
    float aw = ex / sm;
    aws[t] = aw;
#pragma unroll
    for (int c = 0; c < 3; ++c) {
      float kv = aw * cl[t][4 + c];
#pragma unroll
      for (int off = 16; off > 0; off >>= 1) kv += __shfl_xor(kv, off);
      if (t == 0) out[((size_t)(b * 3 + c)) * 512 + m] = kv;
    }
  }
  __syncthreads();

  {
    float gsum = 0.f;
    size_t abase = (size_t)O_AFM + (((size_t)(b * 256 + t)) * 512 + m) * 32;
    float4* ap = (float4*)(out + abase);
#pragma unroll
    for (int p4 = 0; p4 < 8; ++p4) {
      float4 o;
      o.x = embv[4 * p4 + 0] * aws[4 * p4 + 0];
      o.y = embv[4 * p4 + 1] * aws[4 * p4 + 1];
      o.z = embv[4 * p4 + 2] * aws[4 * p4 + 2];
      o.w = embv[4 * p4 + 3] * aws[4 * p4 + 3];
      gsum += o.x; gsum += o.y; gsum += o.z; gsum += o.w;
      ap[p4] = o;
    }
    gcf[((size_t)(b * 256 + t)) * 512 + m] = gsum;
  }
}

// ---------------- kernel 4: MLP head ----------------
__global__ __launch_bounds__(256) void mlp_kernel(
    const float* __restrict__ gcf, const float* __restrict__ w_m1,
    const float* __restrict__ bm1, const float* __restrict__ gm1,
    const float* __restrict__ bbm1, const float* __restrict__ w_m2,
    const float* __restrict__ bm2, const float* __restrict__ gm2,
    const float* __restrict__ bbm2, const float* __restrict__ w_m3,
    const float* __restrict__ bm3, float* __restrict__ out) {
  const int blk = blockIdx.x;
  const int b = blk >> 4;
  const int m0 = (blk & 15) << 5;
  const int t = threadIdx.x;
  __shared__ float sbuf[256 * 36];

#pragma unroll
  for (int i = 0; i < 32; ++i) {
    int c = (t >> 5) + (i << 3);
    int j = t & 31;
    sbuf[c * 36 + j] = gcf[((size_t)(b * 256 + c)) * 512 + m0 + j];
  }
  __syncthreads();

  float acc[32];
#pragma unroll
  for (int j = 0; j < 32; ++j) acc[j] = 0.f;
  for (int c = 0; c < 256; ++c) {
    float wv = w_m1[c * 256 + t];
    const float4* row = (const float4*)&sbuf[c * 36];
#pragma unroll
    for (int j4 = 0; j4 < 8; ++j4) {
      float4 g4 = row[j4];
      acc[4 * j4 + 0] = fmaf(g4.x, wv, acc[4 * j4 + 0]);
      acc[4 * j4 + 1] = fmaf(g4.y, wv, acc[4 * j4 + 1]);
      acc[4 * j4 + 2] = fmaf(g4.z, wv, acc[4 * j4 + 2]);
      acc[4 * j4 + 3] = fmaf(g4.w, wv, acc[4 * j4 + 3]);
    }
  }
  float y[32];
  {
    float gv = gm1[t], bv = bm1[t], bbv = bbm1[t];
#pragma unroll
    for (int j = 0; j < 32; ++j) y[j] = fmaxf(fmaf(gv, acc[j] + bv, bbv), 0.f);
  }
  __syncthreads();
#pragma unroll
  for (int j = 0; j < 32; ++j) sbuf[t * 36 + j] = y[j];
  __syncthreads();

#pragma unroll
  for (int j = 0; j < 32; ++j) acc[j] = 0.f;
  for (int c = 0; c < 256; ++c) {
    float wv = w_m2[c * 256 + t];
    const float4* row = (const float4*)&sbuf[c * 36];
#pragma unroll
    for (int j4 = 0; j4 < 8; ++j4) {
      float4 g4 = row[j4];
      acc[4 * j4 + 0] = fmaf(g4.x, wv, acc[4 * j4 + 0]);
      acc[4 * j4 + 1] = fmaf(g4.y, wv, acc[4 * j4 + 1]);
      acc[4 * j4 + 2] = fmaf(g4.z, wv, acc[4 * j4 + 2]);
      acc[4 * j4 + 3] = fmaf(g4.w, wv, acc[4 * j4 + 3]);
    }
  }
  {
    float gv = gm2[t], bv = bm2[t], bbv = bbm2[t];
#pragma unroll
    for (int j = 0; j < 32; ++j) y[j] = fmaxf(fmaf(gv, acc[j] + bv, bbv), 0.f);
  }
  __syncthreads();
  {
    float w3v = w_m3[t];
#pragma unroll
    for (int j = 0; j < 32; ++j) sbuf[t * 36 + j] = y[j] * w3v;
  }
  __syncthreads();
  if (t < 32) {
    float s = 0.f;
    for (int d = 0; d < 256; ++d) s += sbuf[d * 36 + t];
    s += bm3[0];
    float sal = log1pf(expf(-fabsf(s))) + fmaxf(s, 0.f) + 0.001f;
    out[O_SAL + (size_t)b * 512 + m0 + t] = sal;
  }
}

extern "C" void kernel_launch(void* const* d_in, const int* in_sizes, int n_in,
                              void* d_out, int out_size, void* d_ws, size_t ws_size,
                              hipStream_t stream) {
  (void)in_sizes; (void)n_in; (void)out_size; (void)ws_size;
  const float* x = (const float*)d_in[0];
  const int* rand_idx = (const int*)d_in[1];
  const float* w_e1 = (const float*)d_in[2];
  const float* g1 = (const float*)d_in[3];
  const float* b1 = (const float*)d_in[4];
  const float* w_e2 = (const float*)d_in[5];
  const float* g2 = (const float*)d_in[6];
  const float* b2 = (const float*)d_in[7];
  const float* w_m1 = (const float*)d_in[8];
  const float* bm1 = (const float*)d_in[9];
  const float* gm1 = (const float*)d_in[10];
  const float* bbm1 = (const float*)d_in[11];
  const float* w_m2 = (const float*)d_in[12];
  const float* bm2 = (const float*)d_in[13];
  const float* gm2 = (const float*)d_in[14];
  const float* bbm2 = (const float*)d_in[15];
  const float* w_m3 = (const float*)d_in[16];
  const float* bm3 = (const float*)d_in[17];
  float* out = (float*)d_out;
  char* ws = (char*)d_ws;

  float* node = (float*)ws;                             // 32 KB
  float* sqp = (float*)(ws + 32768);                    // 256 KB
  int* sel = (int*)(ws + 32768 + 262144);               // 256 KB
  float* gcf = (float*)(ws + 32768 + 262144 + 262144);  // 2 MB
  // fps->knn sync flags ALIAS the first 256B of the gcf region (gcf is only
  // written by group_kernel, after the fused kernel; sq zeroes the flags
  // before it). 4 flags, 64B apart. Zero extra workspace bytes.
  unsigned long long* flags = (unsigned long long*)(ws + 32768 + 262144 + 262144);

  sq_kernel<<<256, 256, 0, stream>>>(x, sqp, flags);
  fused_fps_knn<<<256, 1024, 86016, stream>>>(x, node, sqp, rand_idx, sel, flags);
  group_kernel<<<Bn * Mn, 256, 0, stream>>>(x, node, sel, w_e1, g1, b1, w_e2,
                                            g2, b2, out, gcf);
  mlp_kernel<<<64, 256, 0, stream>>>(gcf, w_m1, bm1, gm1, bbm1, w_m2, bm2, gm2,
                                     bbm2, w_m3, bm3, out);
}

// Round 14
// 1817.212 us; speedup vs baseline: 1.0446x; 1.0446x over previous
//
#include <hip/hip_runtime.h>
#include <cstdint>

#define Bn 4
#define Nn 16384
#define Mn 512
#define Kn 32

// output offsets (floats)
#define O_SAL 6144
#define O_RC  8192
#define O_AFM 794624

__device__ __forceinline__ unsigned fkey(float f) {
  unsigned b = __float_as_uint(f);
  return (b & 0x80000000u) ? ~b : (b | 0x80000000u);
}

__device__ __forceinline__ unsigned long long dkey(double d) {
  unsigned long long b = (unsigned long long)__double_as_longlong(d);
  return (b & 0x8000000000000000ull) ? ~b : (b | 0x8000000000000000ull);
}

// ---- kernel 0: per-point squared norm (np: materialized square + seq sum, NO FMA) ----
// Also zeroes the 4 fps->knn sync flags (aliased into the gcf region; runs
// before the fused kernel on the same stream each iteration).
__global__ __launch_bounds__(256) void sq_kernel(const float* __restrict__ x,
                                                 float* __restrict__ sqp,
                                                 unsigned long long* __restrict__ flags) {
#pragma clang fp contract(off)
  int i = blockIdx.x * 256 + threadIdx.x;  // < B*N
  if (blockIdx.x == 0 && threadIdx.x < 4) flags[threadIdx.x * 8] = 0ull;
  float4 v = ((const float4*)x)[i];
  float qx = v.x * v.x;
  float qy = v.y * v.y;
  float qz = v.z * v.z;
  sqp[i] = (qx + qy) + qz;
}

// DPP max step: moved = lane-shuffled v (old = self fallback), then max.
// Values are >= 0 here, so either bound_ctrl semantic (old or 0) is safe.
template <int CTRL>
__device__ __forceinline__ float dppmaxf(float v) {
  int m = __builtin_amdgcn_update_dpp(__float_as_int(v), __float_as_int(v),
                                      CTRL, 0xf, 0xf, false);
  return fmaxf(v, __int_as_float(m));
}

// ------------- fused kernel: fps (blocks 0-3) + knn workers (blocks 4-255) -------------
// r12/r13 post-mortem: fusion overlap works, but fps slowed 884->~1450us.
// Mechanism (from counters): WRITE_SIZE 10-15MB/dispatch (vs 32KB standalone)
// = fps scratch-spill lines evicted from L2 by worker streaming -> spill
// reloads at HBM latency. Also r13's dynamic-LDS occupancy cap never engaged
// (LDS_Block_Size stayed 2560 - the guarded extern use was eliminated).
// Fix both with one stroke: fps branch = r8's LDS-RESIDENT structure
// (px[16]+mind[16] in regs = 32 VGPRs, y/z in a STATIC __shared__ float2
// yz[16384] (128KB), transposed slot(i,t)=i*1024+t -> conflict-free
// ds_read_b64). Zero spills (r8: VGPR 40/SGPR 32/WRITE 32KB) -> immune to
// worker L2 pollution. yz is genuinely used (blockIdx<4 not provably false)
// -> counted in fixed group segment -> ~133KB/block -> HW-guaranteed
// 1 block/CU, 256 blocks = 256 CUs, all co-resident, fps on dedicated CUs.
// Workers (blocks 4-255): item j=(w)+252k -> (m=j>>2,b=j&3); t==0 ACQUIRE
// spin on per-batch chunk flag (s_sleep throttled), barrier; knn body at
// 1024 threads (16 keys/thread) - same distance formula/order, same radix
// counts/threshold, same bitonic, same ties -> bit-identical sel.
// fps publishes chunk counter every 8 steps (t==0, agent RELEASE store).
// Flags alias gcf region (sq zeroes before; group clobbers after).
__global__ __launch_bounds__(1024)
void fused_fps_knn(const float* __restrict__ x, float* __restrict__ node,
                   const float* __restrict__ sqp,
                   const int* __restrict__ rand_idx, int* __restrict__ sel,
                   unsigned long long* __restrict__ flags) {
#pragma clang fp contract(off)
  const int t = threadIdx.x;
  __shared__ float2 yz[16384];  // 128KB static: fps state + 1 block/CU cap
  // fps shared
  __shared__ __align__(16) unsigned long long kkey[2][16];
  // worker shared
  __shared__ unsigned hist[256];
  __shared__ unsigned gsum[16];
  __shared__ unsigned sh_prefix;
  __shared__ int sh_r;
  __shared__ int cnt;
  __shared__ unsigned long long karr[128];

  if (blockIdx.x < 4) {
    // ---------------- fps producer (r8 LDS-resident structure) ----------------
    const int b = blockIdx.x;
    const float4* xb = (const float4*)(x + (size_t)b * Nn * 4);
    float px[16], mind[16];
    const int base = t * 16;
#pragma unroll
    for (int i = 0; i < 16; ++i) {
      float4 v = xb[base + i];
      px[i] = v.x;
      yz[i * 1024 + t] = (float2){v.y, v.z};
      mind[i] = 1e10f;
    }
    float cx, cy, cz;
    {
      float4 v = xb[0];
      cx = v.x; cy = v.y; cz = v.z;
      if (t == 0) ((float4*)node)[b * Mn] = v;
    }
    __syncthreads();  // yz visible
    for (int s = 1; s < Mn; ++s) {
      // pass 1: distance + running min (exact np order, no contraction)
#pragma unroll
      for (int i = 0; i < 16; ++i) {
        float2 p = yz[i * 1024 + t];
        float dx = px[i] - cx;
        float dy = p.x - cy;
        float dz = p.y - cz;
        float qx = dx * dx;
        float qy = dy * dy;
        float qz = dz * dz;
        float d = (qx + qy) + qz;
        mind[i] = fminf(mind[i], d);
      }
      // pass 2: value max tree
      float a0 = fmaxf(mind[0], mind[1]);
      float a1 = fmaxf(mind[2], mind[3]);
      float a2 = fmaxf(mind[4], mind[5]);
      float a3 = fmaxf(mind[6], mind[7]);
      float a4 = fmaxf(mind[8], mind[9]);
      float a5 = fmaxf(mind[10], mind[11]);
      float a6 = fmaxf(mind[12], mind[13]);
      float a7 = fmaxf(mind[14], mind[15]);
      float b0 = fmaxf(a0, a1);
      float b1 = fmaxf(a2, a3);
      float b2 = fmaxf(a4, a5);
      float b3 = fmaxf(a6, a7);
      float bv = fmaxf(fmaxf(b0, b1), fmaxf(b2, b3));
      // pass 3: lowest matching lane-local index (descending scan)
      int isel = 0;
#pragma unroll
      for (int i = 15; i >= 0; --i)
        if (mind[i] == bv) isel = i;
      // wave reduce: value-only DPP max -> lane 63 -> uniform
      float r = bv;
      r = dppmaxf<0x111>(r);
      r = dppmaxf<0x112>(r);
      r = dppmaxf<0x114>(r);
      r = dppmaxf<0x118>(r);
      r = dppmaxf<0x142>(r);
      r = dppmaxf<0x143>(r);
      float wmax = __int_as_float(__builtin_amdgcn_readlane(__float_as_int(r), 63));
      unsigned long long ball = __ballot(bv == wmax);
      int wl = __ffsll(ball) - 1;            // lowest tying lane
      int widx = __builtin_amdgcn_readlane(base + isel, wl);
      if ((t & 63) == 0) {
        kkey[s & 1][t >> 6] =
            ((unsigned long long)(__float_as_uint(wmax) | 0x80000000u) << 32) |
            (unsigned)(~widx);
      }
      __syncthreads();
      {
        // lane-parallel block max over the 16 wave keys
        unsigned long long kk = kkey[s & 1][t & 15];
#pragma unroll
        for (int off = 1; off < 16; off <<= 1) {
          unsigned long long ok = __shfl_xor(kk, off, 16);
          kk = ok > kk ? ok : kk;
        }
        int wi = __builtin_amdgcn_readfirstlane((int)(~(unsigned)(kk & 0xFFFFFFFFu)));
        float4 nv = xb[wi];
        cx = nv.x; cy = nv.y; cz = nv.z;
        if (t == 0) ((float4*)node)[b * Mn + s] = nv;
      }
      // publish completed 8-node chunks (release: prior node stores visible)
      if (((s & 7) == 7) && t == 0) {
        __hip_atomic_store(&flags[b * 8], (unsigned long long)((s + 1) >> 3),
                           __ATOMIC_RELEASE, __HIP_MEMORY_SCOPE_AGENT);
      }
    }
  } else {
    // ---------------- knn workers (1024 threads, 16 keys/thread) ----------------
    const int w = blockIdx.x - 4;
    for (int j = w; j < Bn * Mn; j += 252) {
      const int m = j >> 2;
      const int bb = j & 3;
      // wait for node[bb][m]: chunk (m>>3)+1 published
      if (t == 0) {
        unsigned long long need = (unsigned long long)((m >> 3) + 1);
        while (__hip_atomic_load(&flags[bb * 8], __ATOMIC_ACQUIRE,
                                 __HIP_MEMORY_SCOPE_AGENT) < need)
          __builtin_amdgcn_s_sleep(8);
      }
      __syncthreads();

      const int bm = bb * Mn + m;
      const float4* xb = (const float4*)(x + (size_t)bb * Nn * 4);
      const float* sq_b = sqp + bb * Nn;
      float4 nd = ((const float4*)node)[bm];
      const float nx = nd.x, ny = nd.y, nz = nd.z;
      const float sqmf = (nx * nx + ny * ny) + nz * nz;
      unsigned key[16];
#pragma unroll
      for (int i = 0; i < 16; ++i) {
        int n = t + (i << 10);
        float4 v = xb[n];
        float dot = nx * v.x;
        dot = __builtin_fmaf(ny, v.y, dot);
        dot = __builtin_fmaf(nz, v.z, dot);
        float d2 = (sqmf + sq_b[n]) - 2.0f * dot;
        key[i] = fkey(d2);
      }
      // radix-select rank-95 (byte-wise, 4 passes; same counts/threshold)
      unsigned prefix = 0, pmask = 0;
      int r = 95;
      for (int shift = 24; shift >= 0; shift -= 8) {
        if (t < 256) hist[t] = 0;
        __syncthreads();
#pragma unroll
        for (int i = 0; i < 16; ++i) {
          if ((key[i] & pmask) == prefix)
            atomicAdd(&hist[(key[i] >> shift) & 255], 1u);
        }
        __syncthreads();
        if (t < 16) {
          unsigned ssum = 0;
#pragma unroll
          for (int jj = 0; jj < 16; ++jj) ssum += hist[t * 16 + jj];
          gsum[t] = ssum;
        }
        __syncthreads();
        if (t == 0) {
          int rr = r;
          unsigned g = 0;
          for (unsigned jj = 0; jj < 16; ++jj) {
            int c = (int)gsum[jj];
            if (rr < c) { g = jj; break; }
            rr -= c;
          }
          unsigned bin = g * 16;
          for (unsigned jj = 0; jj < 16; ++jj) {
            int c = (int)hist[g * 16 + jj];
            if (rr < c) { bin = g * 16 + jj; break; }
            rr -= c;
          }
          sh_prefix = prefix | (bin << shift);
          sh_r = rr;
        }
        __syncthreads();
        prefix = sh_prefix;
        r = sh_r;
        pmask |= (0xFFu << shift);
      }
      const unsigned T = prefix;  // collect keys <= T (>=96 candidates; cap 128)
      if (t == 0) cnt = 0;
      __syncthreads();
#pragma unroll
      for (int i = 0; i < 16; ++i) {
        if (key[i] <= T) {
          int pos = atomicAdd(&cnt, 1);
          if (pos < 128) {
            unsigned n = (unsigned)(t + (i << 10));
            karr[pos] = ((unsigned long long)key[i] << 32) | n;
          }
        }
      }
      __syncthreads();
      const int nc = cnt < 128 ? cnt : 128;
      if (t < 128 && t >= nc) karr[t] = ~0ull;
      // 128-wide bitonic sort ascending (identical to standalone version)
      for (int k = 2; k <= 128; k <<= 1) {
        for (int jj = k >> 1; jj > 0; jj >>= 1) {
          __syncthreads();
          if (t < 64) {
            int i = ((t & ~(jj - 1)) << 1) | (t & (jj - 1));
            int ip = i | jj;
            unsigned long long ka = karr[i], kb = karr[ip];
            bool asc = ((i & k) == 0);
            if ((ka > kb) == asc) { karr[i] = kb; karr[ip] = ka; }
          }
        }
      }
      __syncthreads();
      if (t < 32) {
        int ri = rand_idx[t];  // in [0,64)
        sel[bm * 32 + t] = (int)(unsigned)(karr[ri] & 0xFFFFFFFFu);
      }
      __syncthreads();  // protect LDS reuse across items
    }
  }
}

// ---------------- kernel 3: fused group pipeline (r11 version, unchanged) ----------------
__global__ __launch_bounds__(256) void group_kernel(
    const float* __restrict__ x, const float* __restrict__ node,
    const int* __restrict__ sel, const float* __restrict__ w_e1,
    const float* __restrict__ g1, const float* __restrict__ b1,
    const float* __restrict__ w_e2, const float* __restrict__ g2,
    const float* __restrict__ b2, float* __restrict__ out,
    float* __restrict__ gcf) {
#pragma clang fp contract(off)
  const int bm = blockIdx.x;
  const int b = bm >> 9;
  const int m = bm & 511;
  const int t = threadIdx.x;

  __shared__ float cl[32][13];
  __shared__ float h1t[64][36];
  __shared__ float h1p[32][68];
  __shared__ unsigned char nbr[32][8];
  __shared__ double sqs[32];
  __shared__ float part[4][32];
  __shared__ float aws[32];
  __shared__ union U {
    struct {
      unsigned long long keys[32][32];
      float we_a[12][64];
      float we_d[12][64];
      float a1[32][65];
      float cd1[32][65];
    } s;
    float a2[32 * 256];
  } u;

  const float4* xb = (const float4*)(x + (size_t)b * Nn * 4);
  const float4 ndv = ((const float4*)node)[bm];

  if (t < 32) {
    int n = sel[bm * 32 + t];
    float4 v = xb[n];
    float rx = v.x - ndv.x;
    float ry = v.y - ndv.y;
    float rz = v.z - ndv.z;
    float ds = (rx * rx + ry * ry) + rz * rz;
    ds = __fsqrt_rn(ds);
    cl[t][0] = ndv.x; cl[t][1] = ndv.y; cl[t][2] = ndv.z; cl[t][3] = ndv.w;
    cl[t][4] = v.x;   cl[t][5] = v.y;   cl[t][6] = v.z;   cl[t][7] = v.w;
    cl[t][8] = rx;    cl[t][9] = ry;    cl[t][10] = rz;   cl[t][11] = ds;
  }
  for (int i = t; i < 768; i += 256) {
    int row = i >> 6, d = i & 63;
    float wa = w_e1[row * 64 + d];
    float wb = w_e1[(row + 12) * 64 + d];
    u.s.we_a[row][d] = wa;
    u.s.we_d[row][d] = wb - wa;
  }
  __syncthreads();

  for (int i = t; i < 384; i += 256) {
    int c = i >> 5, p = i & 31;
    out[O_RC + (((size_t)(b * 12 + c) * 512) + m) * 32 + p] = cl[p][c];
  }
  if (t < 32) {
    double q[12];
#pragma unroll
    for (int c = 0; c < 12; ++c) {
      double cv = (double)cl[t][c];
      q[c] = cv * cv;
    }
    double s01 = q[0] + q[1];
    double s23 = q[2] + q[3];
    double s45 = q[4] + q[5];
    double s67 = q[6] + q[7];
    double s = (s01 + s23) + (s45 + s67);
    s = s + q[8];
    s = s + q[9];
    s = s + q[10];
    s = s + q[11];
    sqs[t] = s;
  }
  __syncthreads();

  // pairwise d2 (12-d, fp64 order-exact) -> keys
  {
    int p = t >> 3, q0 = (t & 7) << 2;
#pragma unroll
    for (int qq = 0; qq < 4; ++qq) {
      int q = q0 + qq;
      double dot = 0.0;
#pragma unroll
      for (int c = 0; c < 12; ++c)
        dot = dot + (double)cl[p][c] * (double)cl[q][c];
      double d2 = (sqs[p] + sqs[q]) - 2.0 * dot;
      u.s.keys[p][q] = dkey(d2);
    }
  }
  __syncthreads();

  // parallel rank-select top-8 (identical stable lowest-index-ties semantics)
  {
    int p = t >> 3, s8 = t & 7;
    unsigned long long kq0 = u.s.keys[p][s8];
    unsigned long long kq1 = u.s.keys[p][s8 + 8];
    unsigned long long kq2 = u.s.keys[p][s8 + 16];
    unsigned long long kq3 = u.s.keys[p][s8 + 24];
    int r0 = 0, r1 = 0, r2 = 0, r3 = 0;
#pragma unroll
    for (int j = 0; j < 32; ++j) {
      int jj = (j + p) & 31;  // lane-staggered: conflict-free row reads
      unsigned long long kj = u.s.keys[p][jj];
      r0 += (kj < kq0 || (kj == kq0 && jj < s8));
      r1 += (kj < kq1 || (kj == kq1 && jj < s8 + 8));
      r2 += (kj < kq2 || (kj == kq2 && jj < s8 + 16));
      r3 += (kj < kq3 || (kj == kq3 && jj < s8 + 24));
    }
    if (r0 < 8) nbr[p][r0] = (unsigned char)s8;
    if (r1 < 8) nbr[p][r1] = (unsigned char)(s8 + 8);
    if (r2 < 8) nbr[p][r2] = (unsigned char)(s8 + 16);
    if (r3 < 8) nbr[p][r3] = (unsigned char)(s8 + 24);
  }
  {
    int d = t & 63, pg = (t >> 6) << 3;
#pragma unroll
    for (int pp = 0; pp < 8; ++pp) {
      int p = pg + pp;
      float aA = 0.f, aD = 0.f;
#pragma unroll
      for (int c = 0; c < 12; ++c) {
        float xv = cl[p][c];
        aA = fmaf(xv, u.s.we_a[c][d], aA);
        aD = fmaf(xv, u.s.we_d[c][d], aD);
      }
      u.s.a1[p][d] = aA;
      u.s.cd1[p][d] = aD;
    }
  }
  __syncthreads();

  {
    int d = t & 63, pg = (t >> 6) << 3;
    float g1v = g1[d], b1v = b1[d];
#pragma unroll
    for (int pp = 0; pp < 8; ++pp) {
      int p = pg + pp;
      float cd = u.s.cd1[p][d];
      float hm = -1e30f;
#pragma unroll
      for (int k = 0; k < 8; ++k) {
        int j = nbr[p][k];
        float hv = fmaf(g1v, u.s.a1[j][d] + cd, b1v);
        hv = fmaxf(hv, 0.f);
        hm = fmaxf(hm, hv);
      }
      h1t[d][p] = hm;
      h1p[p][d] = hm;
    }
  }
  __syncthreads();

  if (t < 32) {
    double r[8];
#pragma unroll
    for (int j = 0; j < 8; ++j) {
      double hv = (double)h1p[t][j];
      r[j] = hv * hv;
    }
#pragma unroll
    for (int blk = 1; blk < 8; ++blk) {
#pragma unroll
      for (int j = 0; j < 8; ++j) {
        double hv = (double)h1p[t][blk * 8 + j];
        r[j] = r[j] + hv * hv;
      }
    }
    double s01 = r[0] + r[1];
    double s23 = r[2] + r[3];
    double s45 = r[4] + r[5];
    double s67 = r[6] + r[7];
    sqs[t] = (s01 + s23) + (s45 + s67);
  }
  __syncthreads();

  // pairwise d2 over h1 (64-d, fp64, float4-vectorized; same seq order)
  {
    int p = t >> 3, q0 = (t & 7) << 2;
    const float4* rp = (const float4*)&h1p[p][0];
    for (int qq = 0; qq < 4; ++qq) {
      int q = q0 + qq;
      const float4* rq = (const float4*)&h1p[q][0];
      double dot = 0.0;
#pragma unroll
      for (int c4 = 0; c4 < 16; ++c4) {
        float4 av = rp[c4];
        float4 bv = rq[c4];
        dot = dot + (double)av.x * (double)bv.x;
        dot = dot + (double)av.y * (double)bv.y;
        dot = dot + (double)av.z * (double)bv.z;
        dot = dot + (double)av.w * (double)bv.w;
      }
      double d2 = (sqs[p] + sqs[q]) - 2.0 * dot;
      u.s.keys[p][q] = dkey(d2);
    }
  }
  __syncthreads();

  // parallel rank-select top-8 (second neighbor search)
  {
    int p = t >> 3, s8 = t & 7;
    unsigned long long kq0 = u.s.keys[p][s8];
    unsigned long long kq1 = u.s.keys[p][s8 + 8];
    unsigned long long kq2 = u.s.keys[p][s8 + 16];
    unsigned long long kq3 = u.s.keys[p][s8 + 24];
    int r0 = 0, r1 = 0, r2 = 0, r3 = 0;
#pragma unroll
    for (int j = 0; j < 32; ++j) {
      int jj = (j + p) & 31;
      unsigned long long kj = u.s.keys[p][jj];
      r0 += (kj < kq0 || (kj == kq0 && jj < s8));
      r1 += (kj < kq1 || (kj == kq1 && jj < s8 + 8));
      r2 += (kj < kq2 || (kj == kq2 && jj < s8 + 16));
      r3 += (kj < kq3 || (kj == kq3 && jj < s8 + 24));
    }
    if (r0 < 8) nbr[p][r0] = (unsigned char)s8;
    if (r1 < 8) nbr[p][r1] = (unsigned char)(s8 + 8);
    if (r2 < 8) nbr[p][r2] = (unsigned char)(s8 + 16);
    if (r3 < 8) nbr[p][r3] = (unsigned char)(s8 + 24);
  }
  __syncthreads();

  float accD[32];
  float embv[32];
  {
    float accA[32];
#pragma unroll
    for (int p = 0; p < 32; ++p) { accA[p] = 0.f; accD[p] = 0.f; }
    for (int c = 0; c < 64; ++c) {
      float wt = w_e2[c * 256 + t];
      float wb = w_e2[(c + 64) * 256 + t];
      float wd = wb - wt;
      const float4* row = (const float4*)&h1t[c][0];
#pragma unroll
      for (int p4 = 0; p4 < 8; ++p4) {
        float4 hv = row[p4];
        accA[4 * p4 + 0] = fmaf(hv.x, wt, accA[4 * p4 + 0]);
        accA[4 * p4 + 1] = fmaf(hv.y, wt, accA[4 * p4 + 1]);
        accA[4 * p4 + 2] = fmaf(hv.z, wt, accA[4 * p4 + 2]);
        accA[4 * p4 + 3] = fmaf(hv.w, wt, accA[4 * p4 + 3]);
        accD[4 * p4 + 0] = fmaf(hv.x, wd, accD[4 * p4 + 0]);
        accD[4 * p4 + 1] = fmaf(hv.y, wd, accD[4 * p4 + 1]);
        accD[4 * p4 + 2] = fmaf(hv.z, wd, accD[4 * p4 + 2]);
        accD[4 * p4 + 3] = fmaf(hv.w, wd, accD[4 * p4 + 3]);
      }
    }
#pragma unroll
    for (int p = 0; p < 32; ++p) u.a2[p * 256 + t] = accA[p];
  }
  __syncthreads();
  {
    float g2v = g2[t], b2v = b2[t];
#pragma unroll
    for (int p = 0; p < 32; ++p) {
      float cd = accD[p];
      float e = -1e30f;
#pragma unroll
      for (int k = 0; k < 8; ++k) {
        int j = nbr[p][k];
        float hv = fmaf(g2v, u.a2[j * 256 + t] + cd, b2v);
        hv = fmaxf(hv, 0.f);
        e = fmaxf(e, hv);
      }
      embv[p] = e;
    }
  }

#pragma unroll
  for (int p = 0; p < 32; ++p) {
    float v = embv[p];
#pragma unroll
    for (int off = 32; off > 0; off >>= 1) v = fmaxf(v, __shfl_xor(v, off));
    if ((t & 63) == 0) part[t >> 6][p] = v;
  }
  __syncthreads();

  if (t < 32) {
    float x1 = fmaxf(fmaxf(part[0][t], part[1][t]), fmaxf(part[2][t], part[3][t]));
    float mx = x1;
#pragma unroll
    for (int off = 16; off > 0; off >>= 1) mx = fmaxf(mx, __shfl_xor(mx, off));
    float ex = expf(x1 - mx);
    float sm = ex;
#pragma unroll
    for (int off = 16; off > 0; off >>= 1) sm += __shfl_xor(sm, off);
    float aw = ex / sm;
    aws[t] = aw;
#pragma unroll
    for (int c = 0; c < 3; ++c) {
      float kv = aw * cl[t][4 + c];
#pragma unroll
      for (int off = 16; off > 0; off >>= 1) kv += __shfl_xor(kv, off);
      if (t == 0) out[((size_t)(b * 3 + c)) * 512 + m] = kv;
    }
  }
  __syncthreads();

  {
    float gsum = 0.f;
    size_t abase = (size_t)O_AFM + (((size_t)(b * 256 + t)) * 512 + m) * 32;
    float4* ap = (float4*)(out + abase);
#pragma unroll
    for (int p4 = 0; p4 < 8; ++p4) {
      float4 o;
      o.x = embv[4 * p4 + 0] * aws[4 * p4 + 0];
      o.y = embv[4 * p4 + 1] * aws[4 * p4 + 1];
      o.z = embv[4 * p4 + 2] * aws[4 * p4 + 2];
      o.w = embv[4 * p4 + 3] * aws[4 * p4 + 3];
      gsum += o.x; gsum += o.y; gsum += o.z; gsum += o.w;
      ap[p4] = o;
    }
    gcf[((size_t)(b * 256 + t)) * 512 + m] = gsum;
  }
}

// ---------------- kernel 4: MLP head ----------------
__global__ __launch_bounds__(256) void mlp_kernel(
    const float* __restrict__ gcf, const float* __restrict__ w_m1,
    const float* __restrict__ bm1, const float* __restrict__ gm1,
    const float* __restrict__ bbm1, const float* __restrict__ w_m2,
    const float* __restrict__ bm2, const float* __restrict__ gm2,
    const float* __restrict__ bbm2, const float* __restrict__ w_m3,
    const float* __restrict__ bm3, float* __restrict__ out) {
  const int blk = blockIdx.x;
  const int b = blk >> 4;
  const int m0 = (blk & 15) << 5;
  const int t = threadIdx.x;
  __shared__ float sbuf[256 * 36];

#pragma unroll
  for (int i = 0; i < 32; ++i) {
    int c = (t >> 5) + (i << 3);
    int j = t & 31;
    sbuf[c * 36 + j] = gcf[((size_t)(b * 256 + c)) * 512 + m0 + j];
  }
  __syncthreads();

  float acc[32];
#pragma unroll
  for (int j = 0; j < 32; ++j) acc[j] = 0.f;
  for (int c = 0; c < 256; ++c) {
    float wv = w_m1[c * 256 + t];
    const float4* row = (const float4*)&sbuf[c * 36];
#pragma unroll
    for (int j4 = 0; j4 < 8; ++j4) {
      float4 g4 = row[j4];
      acc[4 * j4 + 0] = fmaf(g4.x, wv, acc[4 * j4 + 0]);
      acc[4 * j4 + 1] = fmaf(g4.y, wv, acc[4 * j4 + 1]);
      acc[4 * j4 + 2] = fmaf(g4.z, wv, acc[4 * j4 + 2]);
      acc[4 * j4 + 3] = fmaf(g4.w, wv, acc[4 * j4 + 3]);
    }
  }
  float y[32];
  {
    float gv = gm1[t], bv = bm1[t], bbv = bbm1[t];
#pragma unroll
    for (int j = 0; j < 32; ++j) y[j] = fmaxf(fmaf(gv, acc[j] + bv, bbv), 0.f);
  }
  __syncthreads();
#pragma unroll
  for (int j = 0; j < 32; ++j) sbuf[t * 36 + j] = y[j];
  __syncthreads();

#pragma unroll
  for (int j = 0; j < 32; ++j) acc[j] = 0.f;
  for (int c = 0; c < 256; ++c) {
    float wv = w_m2[c * 256 + t];
    const float4* row = (const float4*)&sbuf[c * 36];
#pragma unroll
    for (int j4 = 0; j4 < 8; ++j4) {
      float4 g4 = row[j4];
      acc[4 * j4 + 0] = fmaf(g4.x, wv, acc[4 * j4 + 0]);
      acc[4 * j4 + 1] = fmaf(g4.y, wv, acc[4 * j4 + 1]);
      acc[4 * j4 + 2] = fmaf(g4.z, wv, acc[4 * j4 + 2]);
      acc[4 * j4 + 3] = fmaf(g4.w, wv, acc[4 * j4 + 3]);
    }
  }
  {
    float gv = gm2[t], bv = bm2[t], bbv = bbm2[t];
#pragma unroll
    for (int j = 0; j < 32; ++j) y[j] = fmaxf(fmaf(gv, acc[j] + bv, bbv), 0.f);
  }
  __syncthreads();
  {
    float w3v = w_m3[t];
#pragma unroll
    for (int j = 0; j < 32; ++j) sbuf[t * 36 + j] = y[j] * w3v;
  }
  __syncthreads();
  if (t < 32) {
    float s = 0.f;
    for (int d = 0; d < 256; ++d) s += sbuf[d * 36 + t];
    s += bm3[0];
    float sal = log1pf(expf(-fabsf(s))) + fmaxf(s, 0.f) + 0.001f;
    out[O_SAL + (size_t)b * 512 + m0 + t] = sal;
  }
}

extern "C" void kernel_launch(void* const* d_in, const int* in_sizes, int n_in,
                              void* d_out, int out_size, void* d_ws, size_t ws_size,
                              hipStream_t stream) {
  (void)in_sizes; (void)n_in; (void)out_size; (void)ws_size;
  const float* x = (const float*)d_in[0];
  const int* rand_idx = (const int*)d_in[1];
  const float* w_e1 = (const float*)d_in[2];
  const float* g1 = (const float*)d_in[3];
  const float* b1 = (const float*)d_in[4];
  const float* w_e2 = (const float*)d_in[5];
  const float* g2 = (const float*)d_in[6];
  const float* b2 = (const float*)d_in[7];
  const float* w_m1 = (const float*)d_in[8];
  const float* bm1 = (const float*)d_in[9];
  const float* gm1 = (const float*)d_in[10];
  const float* bbm1 = (const float*)d_in[11];
  const float* w_m2 = (const float*)d_in[12];
  const float* bm2 = (const float*)d_in[13];
  const float* gm2 = (const float*)d_in[14];
  const float* bbm2 = (const float*)d_in[15];
  const float* w_m3 = (const float*)d_in[16];
  const float* bm3 = (const float*)d_in[17];
  float* out = (float*)d_out;
  char* ws = (char*)d_ws;

  float* node = (float*)ws;                             // 32 KB
  float* sqp = (float*)(ws + 32768);                    // 256 KB
  int* sel = (int*)(ws + 32768 + 262144);               // 256 KB
  float* gcf = (float*)(ws + 32768 + 262144 + 262144);  // 2 MB
  // fps->knn sync flags ALIAS the first 256B of the gcf region (gcf is only
  // written by group_kernel, after the fused kernel; sq zeroes the flags
  // before it). 4 flags, 64B apart. Zero extra workspace bytes.
  unsigned long long* flags = (unsigned long long*)(ws + 32768 + 262144 + 262144);

  sq_kernel<<<256, 256, 0, stream>>>(x, sqp, flags);
  fused_fps_knn<<<256, 1024, 0, stream>>>(x, node, sqp, rand_idx, sel, flags);
  group_kernel<<<Bn * Mn, 256, 0, stream>>>(x, node, sel, w_e1, g1, b1, w_e2,
                                            g2, b2, out, gcf);
  mlp_kernel<<<64, 256, 0, stream>>>(gcf, w_m1, bm1, gm1, bbm1, w_m2, bm2, gm2,
                                     bbm2, w_m3, bm3, out);
}

// Round 15
// 1644.145 us; speedup vs baseline: 1.1545x; 1.1053x over previous
//
#include <hip/hip_runtime.h>
#include <cstdint>

#define Bn 4
#define Nn 16384
#define Mn 512
#define Kn 32

// output offsets (floats)
#define O_SAL 6144
#define O_RC  8192
#define O_AFM 794624

__device__ __forceinline__ unsigned fkey(float f) {
  unsigned b = __float_as_uint(f);
  return (b & 0x80000000u) ? ~b : (b | 0x80000000u);
}

__device__ __forceinline__ unsigned long long dkey(double d) {
  unsigned long long b = (unsigned long long)__double_as_longlong(d);
  return (b & 0x8000000000000000ull) ? ~b : (b | 0x8000000000000000ull);
}

// ---- kernel 0: per-point squared norm (np: materialized square + seq sum, NO FMA) ----
// Also zeroes the 4 fps->knn sync flags (aliased into the gcf region; runs
// before the fused kernel on the same stream each iteration).
__global__ __launch_bounds__(256) void sq_kernel(const float* __restrict__ x,
                                                 float* __restrict__ sqp,
                                                 unsigned long long* __restrict__ flags) {
#pragma clang fp contract(off)
  int i = blockIdx.x * 256 + threadIdx.x;  // < B*N
  if (blockIdx.x == 0 && threadIdx.x < 4) flags[threadIdx.x * 8] = 0ull;
  float4 v = ((const float4*)x)[i];
  float qx = v.x * v.x;
  float qy = v.y * v.y;
  float qz = v.z * v.z;
  sqp[i] = (qx + qy) + qz;
}

// DPP max step: moved = lane-shuffled v (old = self fallback), then max.
// Values are >= 0 here, so either bound_ctrl semantic (old or 0) is safe.
template <int CTRL>
__device__ __forceinline__ float dppmaxf(float v) {
  int m = __builtin_amdgcn_update_dpp(__float_as_int(v), __float_as_int(v),
                                      CTRL, 0xf, 0xf, false);
  return fmaxf(v, __int_as_float(m));
}

// ------------- fused kernel: fps (blocks 0-3) + knn workers (blocks 4-255) -------------
// r12-r14 ladder: overlap works; fps slowdown chased from CU-sharing (r12,
// fixed: 1 block/CU via 128KB static LDS, r14 LDS_Block_Size=133632 confirms)
// through HBM spill-writeback (r13->r14: WRITE 10.4->4.3MB) to the LAST
// remaining global access in the fps loop: the winner reload xb[wi]
// (uniform; L2-hit standalone, but degraded to ~HBM latency by 252 workers
// streaming 640MB through L2/L3 = the residual ~0.6us/step). This round
// makes the fps inner loop MEMORY-FREE:
//   - node workspace now stores INDICES (int); fps's only global op is a
//     fire-and-forget int store by t==0. knn/group read xb[nodeidx[bm]] -
//     one uniform indirection off their critical paths; values bit-identical
//     (node rows are copies of x rows, .w included for group).
//   - winner coords from on-chip state: y,z = yz[(wi&15)*1024+(wi>>4)]
//     (uniform LDS -> broadcast, all threads); x published by the owning
//     thread (t==wi>>4) via compile-time-indexed cndmask scan over px[] (no
//     scratch) into a parity-indexed LDS slot; second barrier; all read cx.
// Worker traffic can no longer touch fps's critical path (pure LDS+VALU).
// Workers: item j=w+252k -> (m=j>>2,b=j&3); t==0 ACQUIRE spin (s_sleep(32),
// 4x less poll traffic), barrier; knn body at 1024 threads - same distance
// formula/order, same radix counts, same bitonic, same ties -> sel
// bit-identical. fps publishes chunk flag every 8 steps (RELEASE, agent).
// Flags alias gcf region (sq zeroes before; group clobbers after).
__global__ __launch_bounds__(1024)
void fused_fps_knn(const float* __restrict__ x, int* __restrict__ nodeidx,
                   const float* __restrict__ sqp,
                   const int* __restrict__ rand_idx, int* __restrict__ sel,
                   unsigned long long* __restrict__ flags) {
#pragma clang fp contract(off)
  const int t = threadIdx.x;
  __shared__ float2 yz[16384];  // 128KB static: fps state + 1 block/CU cap
  // fps shared
  __shared__ __align__(16) unsigned long long kkey[2][16];
  __shared__ float cxs[2];
  // worker shared
  __shared__ unsigned hist[256];
  __shared__ unsigned gsum[16];
  __shared__ unsigned sh_prefix;
  __shared__ int sh_r;
  __shared__ int cnt;
  __shared__ unsigned long long karr[128];

  if (blockIdx.x < 4) {
    // ---------------- fps producer (memory-free inner loop) ----------------
    const int b = blockIdx.x;
    const float4* xb = (const float4*)(x + (size_t)b * Nn * 4);
    float px[16], mind[16];
    const int base = t * 16;
#pragma unroll
    for (int i = 0; i < 16; ++i) {
      float4 v = xb[base + i];
      px[i] = v.x;
      yz[i * 1024 + t] = (float2){v.y, v.z};
      mind[i] = 1e10f;
    }
    float cx, cy, cz;
    {
      float4 v = xb[0];
      cx = v.x; cy = v.y; cz = v.z;
      if (t == 0) nodeidx[b * Mn] = 0;
    }
    __syncthreads();  // yz visible
    for (int s = 1; s < Mn; ++s) {
      // pass 1: distance + running min (exact np order, no contraction)
#pragma unroll
      for (int i = 0; i < 16; ++i) {
        float2 p = yz[i * 1024 + t];
        float dx = px[i] - cx;
        float dy = p.x - cy;
        float dz = p.y - cz;
        float qx = dx * dx;
        float qy = dy * dy;
        float qz = dz * dz;
        float d = (qx + qy) + qz;
        mind[i] = fminf(mind[i], d);
      }
      // pass 2: value max tree
      float a0 = fmaxf(mind[0], mind[1]);
      float a1 = fmaxf(mind[2], mind[3]);
      float a2 = fmaxf(mind[4], mind[5]);
      float a3 = fmaxf(mind[6], mind[7]);
      float a4 = fmaxf(mind[8], mind[9]);
      float a5 = fmaxf(mind[10], mind[11]);
      float a6 = fmaxf(mind[12], mind[13]);
      float a7 = fmaxf(mind[14], mind[15]);
      float b0 = fmaxf(a0, a1);
      float b1 = fmaxf(a2, a3);
      float b2 = fmaxf(a4, a5);
      float b3 = fmaxf(a6, a7);
      float bv = fmaxf(fmaxf(b0, b1), fmaxf(b2, b3));
      // pass 3: lowest matching lane-local index (descending scan)
      int isel = 0;
#pragma unroll
      for (int i = 15; i >= 0; --i)
        if (mind[i] == bv) isel = i;
      // wave reduce: value-only DPP max -> lane 63 -> uniform
      float r = bv;
      r = dppmaxf<0x111>(r);
      r = dppmaxf<0x112>(r);
      r = dppmaxf<0x114>(r);
      r = dppmaxf<0x118>(r);
      r = dppmaxf<0x142>(r);
      r = dppmaxf<0x143>(r);
      float wmax = __int_as_float(__builtin_amdgcn_readlane(__float_as_int(r), 63));
      unsigned long long ball = __ballot(bv == wmax);
      int wl = __ffsll(ball) - 1;            // lowest tying lane
      int widx = __builtin_amdgcn_readlane(base + isel, wl);
      if ((t & 63) == 0) {
        kkey[s & 1][t >> 6] =
            ((unsigned long long)(__float_as_uint(wmax) | 0x80000000u) << 32) |
            (unsigned)(~widx);
      }
      __syncthreads();
      int wi;
      {
        // lane-parallel block max over the 16 wave keys
        unsigned long long kk = kkey[s & 1][t & 15];
#pragma unroll
        for (int off = 1; off < 16; off <<= 1) {
          unsigned long long ok = __shfl_xor(kk, off, 16);
          kk = ok > kk ? ok : kk;
        }
        wi = __builtin_amdgcn_readfirstlane((int)(~(unsigned)(kk & 0xFFFFFFFFu)));
      }
      // winner y,z: uniform LDS read (broadcast, all threads)
      float2 wyz = yz[(wi & 15) * 1024 + (wi >> 4)];
      cy = wyz.x; cz = wyz.y;
      // winner x: owner publishes via compile-time-indexed select (no scratch)
      if (t == (wi >> 4)) {
        float xv = px[0];
#pragma unroll
        for (int i = 15; i >= 1; --i)
          if ((wi & 15) == i) xv = px[i];
        cxs[s & 1] = xv;
      }
      if (t == 0) nodeidx[b * Mn + s] = wi;  // fire-and-forget
      // publish completed 8-node chunks (release: prior nodeidx stores visible)
      if (((s & 7) == 7) && t == 0) {
        __hip_atomic_store(&flags[b * 8], (unsigned long long)((s + 1) >> 3),
                           __ATOMIC_RELEASE, __HIP_MEMORY_SCOPE_AGENT);
      }
      __syncthreads();
      cx = cxs[s & 1];
    }
  } else {
    // ---------------- knn workers (1024 threads, 16 keys/thread) ----------------
    const int w = blockIdx.x - 4;
    for (int j = w; j < Bn * Mn; j += 252) {
      const int m = j >> 2;
      const int bb = j & 3;
      // wait for nodeidx[bb][m]: chunk (m>>3)+1 published
      if (t == 0) {
        unsigned long long need = (unsigned long long)((m >> 3) + 1);
        while (__hip_atomic_load(&flags[bb * 8], __ATOMIC_ACQUIRE,
                                 __HIP_MEMORY_SCOPE_AGENT) < need)
          __builtin_amdgcn_s_sleep(32);
      }
      __syncthreads();

      const int bm = bb * Mn + m;
      const float4* xb = (const float4*)(x + (size_t)bb * Nn * 4);
      const float* sq_b = sqp + bb * Nn;
      int ni = nodeidx[bm];
      float4 nd = xb[ni];
      const float nx = nd.x, ny = nd.y, nz = nd.z;
      const float sqmf = (nx * nx + ny * ny) + nz * nz;
      unsigned key[16];
#pragma unroll
      for (int i = 0; i < 16; ++i) {
        int n = t + (i << 10);
        float4 v = xb[n];
        float dot = nx * v.x;
        dot = __builtin_fmaf(ny, v.y, dot);
        dot = __builtin_fmaf(nz, v.z, dot);
        float d2 = (sqmf + sq_b[n]) - 2.0f * dot;
        key[i] = fkey(d2);
      }
      // radix-select rank-95 (byte-wise, 4 passes; same counts/threshold)
      unsigned prefix = 0, pmask = 0;
      int r = 95;
      for (int shift = 24; shift >= 0; shift -= 8) {
        if (t < 256) hist[t] = 0;
        __syncthreads();
#pragma unroll
        for (int i = 0; i < 16; ++i) {
          if ((key[i] & pmask) == prefix)
            atomicAdd(&hist[(key[i] >> shift) & 255], 1u);
        }
        __syncthreads();
        if (t < 16) {
          unsigned ssum = 0;
#pragma unroll
          for (int jj = 0; jj < 16; ++jj) ssum += hist[t * 16 + jj];
          gsum[t] = ssum;
        }
        __syncthreads();
        if (t == 0) {
          int rr = r;
          unsigned g = 0;
          for (unsigned jj = 0; jj < 16; ++jj) {
            int c = (int)gsum[jj];
            if (rr < c) { g = jj; break; }
            rr -= c;
          }
          unsigned bin = g * 16;
          for (unsigned jj = 0; jj < 16; ++jj) {
            int c = (int)hist[g * 16 + jj];
            if (rr < c) { bin = g * 16 + jj; break; }
            rr -= c;
          }
          sh_prefix = prefix | (bin << shift);
          sh_r = rr;
        }
        __syncthreads();
        prefix = sh_prefix;
        r = sh_r;
        pmask |= (0xFFu << shift);
      }
      const unsigned T = prefix;  // collect keys <= T (>=96 candidates; cap 128)
      if (t == 0) cnt = 0;
      __syncthreads();
#pragma unroll
      for (int i = 0; i < 16; ++i) {
        if (key[i] <= T) {
          int pos = atomicAdd(&cnt, 1);
          if (pos < 128) {
            unsigned n = (unsigned)(t + (i << 10));
            karr[pos] = ((unsigned long long)key[i] << 32) | n;
          }
        }
      }
      __syncthreads();
      const int nc = cnt < 128 ? cnt : 128;
      if (t < 128 && t >= nc) karr[t] = ~0ull;
      // 128-wide bitonic sort ascending (identical to standalone version)
      for (int k = 2; k <= 128; k <<= 1) {
        for (int jj = k >> 1; jj > 0; jj >>= 1) {
          __syncthreads();
          if (t < 64) {
            int i = ((t & ~(jj - 1)) << 1) | (t & (jj - 1));
            int ip = i | jj;
            unsigned long long ka = karr[i], kb = karr[ip];
            bool asc = ((i & k) == 0);
            if ((ka > kb) == asc) { karr[i] = kb; karr[ip] = ka; }
          }
        }
      }
      __syncthreads();
      if (t < 32) {
        int ri = rand_idx[t];  // in [0,64)
        sel[bm * 32 + t] = (int)(unsigned)(karr[ri] & 0xFFFFFFFFu);
      }
      __syncthreads();  // protect LDS reuse across items
    }
  }
}

// ---------------- kernel 3: fused group pipeline (nodeidx indirection) ----------------
__global__ __launch_bounds__(256) void group_kernel(
    const float* __restrict__ x, const int* __restrict__ nodeidx,
    const int* __restrict__ sel, const float* __restrict__ w_e1,
    const float* __restrict__ g1, const float* __restrict__ b1,
    const float* __restrict__ w_e2, const float* __restrict__ g2,
    const float* __restrict__ b2, float* __restrict__ out,
    float* __restrict__ gcf) {
#pragma clang fp contract(off)
  const int bm = blockIdx.x;
  const int b = bm >> 9;
  const int m = bm & 511;
  const int t = threadIdx.x;

  __shared__ float cl[32][13];
  __shared__ float h1t[64][36];
  __shared__ float h1p[32][68];
  __shared__ unsigned char nbr[32][8];
  __shared__ double sqs[32];
  __shared__ float part[4][32];
  __shared__ float aws[32];
  __shared__ union U {
    struct {
      unsigned long long keys[32][32];
      float we_a[12][64];
      float we_d[12][64];
      float a1[32][65];
      float cd1[32][65];
    } s;
    float a2[32 * 256];
  } u;

  const float4* xb = (const float4*)(x + (size_t)b * Nn * 4);
  const float4 ndv = xb[nodeidx[bm]];  // same values as before (copy of x row)

  if (t < 32) {
    int n = sel[bm * 32 + t];
    float4 v = xb[n];
    float rx = v.x - ndv.x;
    float ry = v.y - ndv.y;
    float rz = v.z - ndv.z;
    float ds = (rx * rx + ry * ry) + rz * rz;
    ds = __fsqrt_rn(ds);
    cl[t][0] = ndv.x; cl[t][1] = ndv.y; cl[t][2] = ndv.z; cl[t][3] = ndv.w;
    cl[t][4] = v.x;   cl[t][5] = v.y;   cl[t][6] = v.z;   cl[t][7] = v.w;
    cl[t][8] = rx;    cl[t][9] = ry;    cl[t][10] = rz;   cl[t][11] = ds;
  }
  for (int i = t; i < 768; i += 256) {
    int row = i >> 6, d = i & 63;
    float wa = w_e1[row * 64 + d];
    float wb = w_e1[(row + 12) * 64 + d];
    u.s.we_a[row][d] = wa;
    u.s.we_d[row][d] = wb - wa;
  }
  __syncthreads();

  for (int i = t; i < 384; i += 256) {
    int c = i >> 5, p = i & 31;
    out[O_RC + (((size_t)(b * 12 + c) * 512) + m) * 32 + p] = cl[p][c];
  }
  if (t < 32) {
    double q[12];
#pragma unroll
    for (int c = 0; c < 12; ++c) {
      double cv = (double)cl[t][c];
      q[c] = cv * cv;
    }
    double s01 = q[0] + q[1];
    double s23 = q[2] + q[3];
    double s45 = q[4] + q[5];
    double s67 = q[6] + q[7];
    double s = (s01 + s23) + (s45 + s67);
    s = s + q[8];
    s = s + q[9];
    s = s + q[10];
    s = s + q[11];
    sqs[t] = s;
  }
  __syncthreads();

  // pairwise d2 (12-d, fp64 order-exact) -> keys
  {
    int p = t >> 3, q0 = (t & 7) << 2;
#pragma unroll
    for (int qq = 0; qq < 4; ++qq) {
      int q = q0 + qq;
      double dot = 0.0;
#pragma unroll
      for (int c = 0; c < 12; ++c)
        dot = dot + (double)cl[p][c] * (double)cl[q][c];
      double d2 = (sqs[p] + sqs[q]) - 2.0 * dot;
      u.s.keys[p][q] = dkey(d2);
    }
  }
  __syncthreads();

  // parallel rank-select top-8 (identical stable lowest-index-ties semantics)
  {
    int p = t >> 3, s8 = t & 7;
    unsigned long long kq0 = u.s.keys[p][s8];
    unsigned long long kq1 = u.s.keys[p][s8 + 8];
    unsigned long long kq2 = u.s.keys[p][s8 + 16];
    unsigned long long kq3 = u.s.keys[p][s8 + 24];
    int r0 = 0, r1 = 0, r2 = 0, r3 = 0;
#pragma unroll
    for (int j = 0; j < 32; ++j) {
      int jj = (j + p) & 31;  // lane-staggered: conflict-free row reads
      unsigned long long kj = u.s.keys[p][jj];
      r0 += (kj < kq0 || (kj == kq0 && jj < s8));
      r1 += (kj < kq1 || (kj == kq1 && jj < s8 + 8));
      r2 += (kj < kq2 || (kj == kq2 && jj < s8 + 16));
      r3 += (kj < kq3 || (kj == kq3 && jj < s8 + 24));
    }
    if (r0 < 8) nbr[p][r0] = (unsigned char)s8;
    if (r1 < 8) nbr[p][r1] = (unsigned char)(s8 + 8);
    if (r2 < 8) nbr[p][r2] = (unsigned char)(s8 + 16);
    if (r3 < 8) nbr[p][r3] = (unsigned char)(s8 + 24);
  }
  {
    int d = t & 63, pg = (t >> 6) << 3;
#pragma unroll
    for (int pp = 0; pp < 8; ++pp) {
      int p = pg + pp;
      float aA = 0.f, aD = 0.f;
#pragma unroll
      for (int c = 0; c < 12; ++c) {
        float xv = cl[p][c];
        aA = fmaf(xv, u.s.we_a[c][d], aA);
        aD = fmaf(xv, u.s.we_d[c][d], aD);
      }
      u.s.a1[p][d] = aA;
      u.s.cd1[p][d] = aD;
    }
  }
  __syncthreads();

  {
    int d = t & 63, pg = (t >> 6) << 3;
    float g1v = g1[d], b1v = b1[d];
#pragma unroll
    for (int pp = 0; pp < 8; ++pp) {
      int p = pg + pp;
      float cd = u.s.cd1[p][d];
      float hm = -1e30f;
#pragma unroll
      for (int k = 0; k < 8; ++k) {
        int j = nbr[p][k];
        float hv = fmaf(g1v, u.s.a1[j][d] + cd, b1v);
        hv = fmaxf(hv, 0.f);
        hm = fmaxf(hm, hv);
      }
      h1t[d][p] = hm;
      h1p[p][d] = hm;
    }
  }
  __syncthreads();

  if (t < 32) {
    double r[8];
#pragma unroll
    for (int j = 0; j < 8; ++j) {
      double hv = (double)h1p[t][j];
      r[j] = hv * hv;
    }
#pragma unroll
    for (int blk = 1; blk < 8; ++blk) {
#pragma unroll
      for (int j = 0; j < 8; ++j) {
        double hv = (double)h1p[t][blk * 8 + j];
        r[j] = r[j] + hv * hv;
      }
    }
    double s01 = r[0] + r[1];
    double s23 = r[2] + r[3];
    double s45 = r[4] + r[5];
    double s67 = r[6] + r[7];
    sqs[t] = (s01 + s23) + (s45 + s67);
  }
  __syncthreads();

  // pairwise d2 over h1 (64-d, fp64, float4-vectorized; same seq order)
  {
    int p = t >> 3, q0 = (t & 7) << 2;
    const float4* rp = (const float4*)&h1p[p][0];
    for (int qq = 0; qq < 4; ++qq) {
      int q = q0 + qq;
      const float4* rq = (const float4*)&h1p[q][0];
      double dot = 0.0;
#pragma unroll
      for (int c4 = 0; c4 < 16; ++c4) {
        float4 av = rp[c4];
        float4 bv = rq[c4];
        dot = dot + (double)av.x * (double)bv.x;
        dot = dot + (double)av.y * (double)bv.y;
        dot = dot + (double)av.z * (double)bv.z;
        dot = dot + (double)av.w * (double)bv.w;
      }
      double d2 = (sqs[p] + sqs[q]) - 2.0 * dot;
      u.s.keys[p][q] = dkey(d2);
    }
  }
  __syncthreads();

  // parallel rank-select top-8 (second neighbor search)
  {
    int p = t >> 3, s8 = t & 7;
    unsigned long long kq0 = u.s.keys[p][s8];
    unsigned long long kq1 = u.s.keys[p][s8 + 8];
    unsigned long long kq2 = u.s.keys[p][s8 + 16];
    unsigned long long kq3 = u.s.keys[p][s8 + 24];
    int r0 = 0, r1 = 0, r2 = 0, r3 = 0;
#pragma unroll
    for (int j = 0; j < 32; ++j) {
      int jj = (j + p) & 31;
      unsigned long long kj = u.s.keys[p][jj];
      r0 += (kj < kq0 || (kj == kq0 && jj < s8));
      r1 += (kj < kq1 || (kj == kq1 && jj < s8 + 8));
      r2 += (kj < kq2 || (kj == kq2 && jj < s8 + 16));
      r3 += (kj < kq3 || (kj == kq3 && jj < s8 + 24));
    }
    if (r0 < 8) nbr[p][r0] = (unsigned char)s8;
    if (r1 < 8) nbr[p][r1] = (unsigned char)(s8 + 8);
    if (r2 < 8) nbr[p][r2] = (unsigned char)(s8 + 16);
    if (r3 < 8) nbr[p][r3] = (unsigned char)(s8 + 24);
  }
  __syncthreads();

  float accD[32];
  float embv[32];
  {
    float accA[32];
#pragma unroll
    for (int p = 0; p < 32; ++p) { accA[p] = 0.f; accD[p] = 0.f; }
    for (int c = 0; c < 64; ++c) {
      float wt = w_e2[c * 256 + t];
      float wb = w_e2[(c + 64) * 256 + t];
      float wd = wb - wt;
      const float4* row = (const float4*)&h1t[c][0];
#pragma unroll
      for (int p4 = 0; p4 < 8; ++p4) {
        float4 hv = row[p4];
        accA[4 * p4 + 0] = fmaf(hv.x, wt, accA[4 * p4 + 0]);
        accA[4 * p4 + 1] = fmaf(hv.y, wt, accA[4 * p4 + 1]);
        accA[4 * p4 + 2] = fmaf(hv.z, wt, accA[4 * p4 + 2]);
        accA[4 * p4 + 3] = fmaf(hv.w, wt, accA[4 * p4 + 3]);
        accD[4 * p4 + 0] = fmaf(hv.x, wd, accD[4 * p4 + 0]);
        accD[4 * p4 + 1] = fmaf(hv.y, wd, accD[4 * p4 + 1]);
        accD[4 * p4 + 2] = fmaf(hv.z, wd, accD[4 * p4 + 2]);
        accD[4 * p4 + 3] = fmaf(hv.w, wd, accD[4 * p4 + 3]);
      }
    }
#pragma unroll
    for (int p = 0; p < 32; ++p) u.a2[p * 256 + t] = accA[p];
  }
  __syncthreads();
  {
    float g2v = g2[t], b2v = b2[t];
#pragma unroll
    for (int p = 0; p < 32; ++p) {
      float cd = accD[p];
      float e = -1e30f;
#pragma unroll
      for (int k = 0; k < 8; ++k) {
        int j = nbr[p][k];
        float hv = fmaf(g2v, u.a2[j * 256 + t] + cd, b2v);
        hv = fmaxf(hv, 0.f);
        e = fmaxf(e, hv);
      }
      embv[p] = e;
    }
  }

#pragma unroll
  for (int p = 0; p < 32; ++p) {
    float v = embv[p];
#pragma unroll
    for (int off = 32; off > 0; off >>= 1) v = fmaxf(v, __shfl_xor(v, off));
    if ((t & 63) == 0) part[t >> 6][p] = v;
  }
  __syncthreads();

  if (t < 32) {
    float x1 = fmaxf(fmaxf(part[0][t], part[1][t]), fmaxf(part[2][t], part[3][t]));
    float mx = x1;
#pragma unroll
    for (int off = 16; off > 0; off >>= 1) mx = fmaxf(mx, __shfl_xor(mx, off));
    float ex = expf(x1 - mx);
    float sm = ex;
#pragma unroll
    for (int off = 16; off > 0; off >>= 1) sm += __shfl_xor(sm, off);
    float aw = ex / sm;
    aws[t] = aw;
#pragma unroll
    for (int c = 0; c < 3; ++c) {
      float kv = aw * cl[t][4 + c];
#pragma unroll
      for (int off = 16; off > 0; off >>= 1) kv += __shfl_xor(kv, off);
      if (t == 0) out[((size_t)(b * 3 + c)) * 512 + m] = kv;
    }
  }
  __syncthreads();

  {
    float gsum = 0.f;
    size_t abase = (size_t)O_AFM + (((size_t)(b * 256 + t)) * 512 + m) * 32;
    float4* ap = (float4*)(out + abase);
#pragma unroll
    for (int p4 = 0; p4 < 8; ++p4) {
      float4 o;
      o.x = embv[4 * p4 + 0] * aws[4 * p4 + 0];
      o.y = embv[4 * p4 + 1] * aws[4 * p4 + 1];
      o.z = embv[4 * p4 + 2] * aws[4 * p4 + 2];
      o.w = embv[4 * p4 + 3] * aws[4 * p4 + 3];
      gsum += o.x; gsum += o.y; gsum += o.z; gsum += o.w;
      ap[p4] = o;
    }
    gcf[((size_t)(b * 256 + t)) * 512 + m] = gsum;
  }
}

// ---------------- kernel 4: MLP head ----------------
__global__ __launch_bounds__(256) void mlp_kernel(
    const float* __restrict__ gcf, const float* __restrict__ w_m1,
    const float* __restrict__ bm1, const float* __restrict__ gm1,
    const float* __restrict__ bbm1, const float* __restrict__ w_m2,
    const float* __restrict__ bm2, const float* __restrict__ gm2,
    const float* __restrict__ bbm2, const float* __restrict__ w_m3,
    const float* __restrict__ bm3, float* __restrict__ out) {
  const int blk = blockIdx.x;
  const int b = blk >> 4;
  const int m0 = (blk & 15) << 5;
  const int t = threadIdx.x;
  __shared__ float sbuf[256 * 36];

#pragma unroll
  for (int i = 0; i < 32; ++i) {
    int c = (t >> 5) + (i << 3);
    int j = t & 31;
    sbuf[c * 36 + j] = gcf[((size_t)(b * 256 + c)) * 512 + m0 + j];
  }
  __syncthreads();

  float acc[32];
#pragma unroll
  for (int j = 0; j < 32; ++j) acc[j] = 0.f;
  for (int c = 0; c < 256; ++c) {
    float wv = w_m1[c * 256 + t];
    const float4* row = (const float4*)&sbuf[c * 36];
#pragma unroll
    for (int j4 = 0; j4 < 8; ++j4) {
      float4 g4 = row[j4];
      acc[4 * j4 + 0] = fmaf(g4.x, wv, acc[4 * j4 + 0]);
      acc[4 * j4 + 1] = fmaf(g4.y, wv, acc[4 * j4 + 1]);
      acc[4 * j4 + 2] = fmaf(g4.z, wv, acc[4 * j4 + 2]);
      acc[4 * j4 + 3] = fmaf(g4.w, wv, acc[4 * j4 + 3]);
    }
  }
  float y[32];
  {
    float gv = gm1[t], bv = bm1[t], bbv = bbm1[t];
#pragma unroll
    for (int j = 0; j < 32; ++j) y[j] = fmaxf(fmaf(gv, acc[j] + bv, bbv), 0.f);
  }
  __syncthreads();
#pragma unroll
  for (int j = 0; j < 32; ++j) sbuf[t * 36 + j] = y[j];
  __syncthreads();

#pragma unroll
  for (int j = 0; j < 32; ++j) acc[j] = 0.f;
  for (int c = 0; c < 256; ++c) {
    float wv = w_m2[c * 256 + t];
    const float4* row = (const float4*)&sbuf[c * 36];
#pragma unroll
    for (int j4 = 0; j4 < 8; ++j4) {
      float4 g4 = row[j4];
      acc[4 * j4 + 0] = fmaf(g4.x, wv, acc[4 * j4 + 0]);
      acc[4 * j4 + 1] = fmaf(g4.y, wv, acc[4 * j4 + 1]);
      acc[4 * j4 + 2] = fmaf(g4.z, wv, acc[4 * j4 + 2]);
      acc[4 * j4 + 3] = fmaf(g4.w, wv, acc[4 * j4 + 3]);
    }
  }
  {
    float gv = gm2[t], bv = bm2[t], bbv = bbm2[t];
#pragma unroll
    for (int j = 0; j < 32; ++j) y[j] = fmaxf(fmaf(gv, acc[j] + bv, bbv), 0.f);
  }
  __syncthreads();
  {
    float w3v = w_m3[t];
#pragma unroll
    for (int j = 0; j < 32; ++j) sbuf[t * 36 + j] = y[j] * w3v;
  }
  __syncthreads();
  if (t < 32) {
    float s = 0.f;
    for (int d = 0; d < 256; ++d) s += sbuf[d * 36 + t];
    s += bm3[0];
    float sal = log1pf(expf(-fabsf(s))) + fmaxf(s, 0.f) + 0.001f;
    out[O_SAL + (size_t)b * 512 + m0 + t] = sal;
  }
}

extern "C" void kernel_launch(void* const* d_in, const int* in_sizes, int n_in,
                              void* d_out, int out_size, void* d_ws, size_t ws_size,
                              hipStream_t stream) {
  (void)in_sizes; (void)n_in; (void)out_size; (void)ws_size;
  const float* x = (const float*)d_in[0];
  const int* rand_idx = (const int*)d_in[1];
  const float* w_e1 = (const float*)d_in[2];
  const float* g1 = (const float*)d_in[3];
  const float* b1 = (const float*)d_in[4];
  const float* w_e2 = (const float*)d_in[5];
  const float* g2 = (const float*)d_in[6];
  const float* b2 = (const float*)d_in[7];
  const float* w_m1 = (const float*)d_in[8];
  const float* bm1 = (const float*)d_in[9];
  const float* gm1 = (const float*)d_in[10];
  const float* bbm1 = (const float*)d_in[11];
  const float* w_m2 = (const float*)d_in[12];
  const float* bm2 = (const float*)d_in[13];
  const float* gm2 = (const float*)d_in[14];
  const float* bbm2 = (const float*)d_in[15];
  const float* w_m3 = (const float*)d_in[16];
  const float* bm3 = (const float*)d_in[17];
  float* out = (float*)d_out;
  char* ws = (char*)d_ws;

  int* nodeidx = (int*)ws;                              // 8 KB used (32 KB region)
  float* sqp = (float*)(ws + 32768);                    // 256 KB
  int* sel = (int*)(ws + 32768 + 262144);               // 256 KB
  float* gcf = (float*)(ws + 32768 + 262144 + 262144);  // 2 MB
  // fps->knn sync flags ALIAS the first 256B of the gcf region (gcf is only
  // written by group_kernel, after the fused kernel; sq zeroes the flags
  // before it). 4 flags, 64B apart. Zero extra workspace bytes.
  unsigned long long* flags = (unsigned long long*)(ws + 32768 + 262144 + 262144);

  sq_kernel<<<256, 256, 0, stream>>>(x, sqp, flags);
  fused_fps_knn<<<256, 1024, 0, stream>>>(x, nodeidx, sqp, rand_idx, sel, flags);
  group_kernel<<<Bn * Mn, 256, 0, stream>>>(x, nodeidx, sel, w_e1, g1, b1, w_e2,
                                            g2, b2, out, gcf);
  mlp_kernel<<<64, 256, 0, stream>>>(gcf, w_m1, bm1, gm1, bbm1, w_m2, bm2, gm2,
                                     bbm2, w_m3, bm3, out);
}

// Round 16
// 1625.862 us; speedup vs baseline: 1.1675x; 1.0112x over previous
//
#include <hip/hip_runtime.h>
#include <cstdint>

#define Bn 4
#define Nn 16384
#define Mn 512
#define Kn 32

// output offsets (floats)
#define O_SAL 6144
#define O_RC  8192
#define O_AFM 794624

__device__ __forceinline__ unsigned fkey(float f) {
  unsigned b = __float_as_uint(f);
  return (b & 0x80000000u) ? ~b : (b | 0x80000000u);
}

__device__ __forceinline__ unsigned long long dkey(double d) {
  unsigned long long b = (unsigned long long)__double_as_longlong(d);
  return (b & 0x8000000000000000ull) ? ~b : (b | 0x8000000000000000ull);
}

// ---- kernel 0: per-point squared norm (np: materialized square + seq sum, NO FMA) ----
// Also zeroes the 4 fps->knn sync flags.
__global__ __launch_bounds__(256) void sq_kernel(const float* __restrict__ x,
                                                 float* __restrict__ sqp,
                                                 unsigned long long* __restrict__ flags) {
#pragma clang fp contract(off)
  int i = blockIdx.x * 256 + threadIdx.x;  // < B*N
  if (blockIdx.x == 0 && threadIdx.x < 4) flags[threadIdx.x * 8] = 0ull;
  float4 v = ((const float4*)x)[i];
  float qx = v.x * v.x;
  float qy = v.y * v.y;
  float qz = v.z * v.z;
  sqp[i] = (qx + qy) + qz;
}

// DPP max step: moved = lane-shuffled v (old = self fallback), then max.
// Values are >= 0 here, so either bound_ctrl semantic (old or 0) is safe.
template <int CTRL>
__device__ __forceinline__ float dppmaxf(float v) {
  int m = __builtin_amdgcn_update_dpp(__float_as_int(v), __float_as_int(v),
                                      CTRL, 0xf, 0xf, false);
  return fmaxf(v, __int_as_float(m));
}

// ------------- fused kernel: fps (blocks 0-3) + knn workers (blocks 4-255) -------------
// r12-r15 ladder: CU-sharing fixed (1 block/CU via 128KB static LDS),
// HBM spill-writeback fixed (LDS-resident fps state), winner reload fixed
// (memory-free loop, nodeidx store only). r15 fused = 1115us; the remaining
// ~+130us vs r8-standalone is the SECOND per-step barrier introduced by the
// owner-publish cx scheme. This round: SINGLE-barrier winner publication.
//   - per wave, the winning lane ((t&63)==wl from the intra-wave ballot)
//     writes its px[isel] (compile-time cndmask scan, no scratch) into
//     parity-buffered pxs[s&1][wave] BEFORE the barrier, alongside the wave
//     leader's kkey write.
//   - after the one barrier: block-reduce kkey -> wi; winning WAVE = wi>>10
//     (widx = t*16+isel => wave = widx>>10); cx = pxs[s&1][wi>>10];
//     cy,cz = yz[(wi&15)*1024+(wi>>4)] - uniform LDS broadcasts, no second
//     barrier, no global loads. Parity buffering makes step-s reads vs
//     step-s+1 writes race-free (same scheme as kkey).
// Workers: unchanged (item j=w+252k; ACQUIRE spin s_sleep(32); 1024-thread
// knn body; same distance formula/order, radix counts, bitonic, ties ->
// sel bit-identical). fps publishes chunk flag every 8 steps (RELEASE).
// Flags alias gcf region (sq zeroes before; group clobbers after).
__global__ __launch_bounds__(1024)
void fused_fps_knn(const float* __restrict__ x, int* __restrict__ nodeidx,
                   const float* __restrict__ sqp,
                   const int* __restrict__ rand_idx, int* __restrict__ sel,
                   unsigned long long* __restrict__ flags) {
#pragma clang fp contract(off)
  const int t = threadIdx.x;
  __shared__ float2 yz[16384];  // 128KB static: fps state + 1 block/CU cap
  // fps shared
  __shared__ __align__(16) unsigned long long kkey[2][16];
  __shared__ float pxs[2][16];
  // worker shared
  __shared__ unsigned hist[256];
  __shared__ unsigned gsum[16];
  __shared__ unsigned sh_prefix;
  __shared__ int sh_r;
  __shared__ int cnt;
  __shared__ unsigned long long karr[128];

  if (blockIdx.x < 4) {
    // ---------------- fps producer (memory-free, single-barrier loop) ----------------
    const int b = blockIdx.x;
    const float4* xb = (const float4*)(x + (size_t)b * Nn * 4);
    float px[16], mind[16];
    const int base = t * 16;
#pragma unroll
    for (int i = 0; i < 16; ++i) {
      float4 v = xb[base + i];
      px[i] = v.x;
      yz[i * 1024 + t] = (float2){v.y, v.z};
      mind[i] = 1e10f;
    }
    float cx, cy, cz;
    {
      float4 v = xb[0];
      cx = v.x; cy = v.y; cz = v.z;
      if (t == 0) nodeidx[b * Mn] = 0;
    }
    __syncthreads();  // yz visible
    for (int s = 1; s < Mn; ++s) {
      // pass 1: distance + running min (exact np order, no contraction)
#pragma unroll
      for (int i = 0; i < 16; ++i) {
        float2 p = yz[i * 1024 + t];
        float dx = px[i] - cx;
        float dy = p.x - cy;
        float dz = p.y - cz;
        float qx = dx * dx;
        float qy = dy * dy;
        float qz = dz * dz;
        float d = (qx + qy) + qz;
        mind[i] = fminf(mind[i], d);
      }
      // pass 2: value max tree
      float a0 = fmaxf(mind[0], mind[1]);
      float a1 = fmaxf(mind[2], mind[3]);
      float a2 = fmaxf(mind[4], mind[5]);
      float a3 = fmaxf(mind[6], mind[7]);
      float a4 = fmaxf(mind[8], mind[9]);
      float a5 = fmaxf(mind[10], mind[11]);
      float a6 = fmaxf(mind[12], mind[13]);
      float a7 = fmaxf(mind[14], mind[15]);
      float b0 = fmaxf(a0, a1);
      float b1 = fmaxf(a2, a3);
      float b2 = fmaxf(a4, a5);
      float b3 = fmaxf(a6, a7);
      float bv = fmaxf(fmaxf(b0, b1), fmaxf(b2, b3));
      // pass 3: lowest matching lane-local index (descending scan)
      int isel = 0;
#pragma unroll
      for (int i = 15; i >= 0; --i)
        if (mind[i] == bv) isel = i;
      // own candidate x via compile-time-indexed select (no scratch)
      float pxsel = px[0];
#pragma unroll
      for (int i = 15; i >= 1; --i)
        if (isel == i) pxsel = px[i];
      // wave reduce: value-only DPP max -> lane 63 -> uniform
      float r = bv;
      r = dppmaxf<0x111>(r);
      r = dppmaxf<0x112>(r);
      r = dppmaxf<0x114>(r);
      r = dppmaxf<0x118>(r);
      r = dppmaxf<0x142>(r);
      r = dppmaxf<0x143>(r);
      float wmax = __int_as_float(__builtin_amdgcn_readlane(__float_as_int(r), 63));
      unsigned long long ball = __ballot(bv == wmax);
      int wl = __ffsll(ball) - 1;            // lowest tying lane
      int widx = __builtin_amdgcn_readlane(base + isel, wl);
      if ((t & 63) == 0) {
        kkey[s & 1][t >> 6] =
            ((unsigned long long)(__float_as_uint(wmax) | 0x80000000u) << 32) |
            (unsigned)(~widx);
      }
      if ((t & 63) == wl) pxs[s & 1][t >> 6] = pxsel;  // wave winner publishes x
      __syncthreads();
      {
        // lane-parallel block max over the 16 wave keys
        unsigned long long kk = kkey[s & 1][t & 15];
#pragma unroll
        for (int off = 1; off < 16; off <<= 1) {
          unsigned long long ok = __shfl_xor(kk, off, 16);
          kk = ok > kk ? ok : kk;
        }
        int wi = __builtin_amdgcn_readfirstlane((int)(~(unsigned)(kk & 0xFFFFFFFFu)));
        // winner coords: all from on-chip state, uniform broadcasts
        cx = pxs[s & 1][wi >> 10];
        float2 wyz = yz[(wi & 15) * 1024 + (wi >> 4)];
        cy = wyz.x; cz = wyz.y;
        if (t == 0) {
          nodeidx[b * Mn + s] = wi;  // fire-and-forget
          if ((s & 7) == 7) {
            __hip_atomic_store(&flags[b * 8], (unsigned long long)((s + 1) >> 3),
                               __ATOMIC_RELEASE, __HIP_MEMORY_SCOPE_AGENT);
          }
        }
      }
    }
  } else {
    // ---------------- knn workers (1024 threads, 16 keys/thread) ----------------
    const int w = blockIdx.x - 4;
    for (int j = w; j < Bn * Mn; j += 252) {
      const int m = j >> 2;
      const int bb = j & 3;
      // wait for nodeidx[bb][m]: chunk (m>>3)+1 published
      if (t == 0) {
        unsigned long long need = (unsigned long long)((m >> 3) + 1);
        while (__hip_atomic_load(&flags[bb * 8], __ATOMIC_ACQUIRE,
                                 __HIP_MEMORY_SCOPE_AGENT) < need)
          __builtin_amdgcn_s_sleep(32);
      }
      __syncthreads();

      const int bm = bb * Mn + m;
      const float4* xb = (const float4*)(x + (size_t)bb * Nn * 4);
      const float* sq_b = sqp + bb * Nn;
      int ni = nodeidx[bm];
      float4 nd = xb[ni];
      const float nx = nd.x, ny = nd.y, nz = nd.z;
      const float sqmf = (nx * nx + ny * ny) + nz * nz;
      unsigned key[16];
#pragma unroll
      for (int i = 0; i < 16; ++i) {
        int n = t + (i << 10);
        float4 v = xb[n];
        float dot = nx * v.x;
        dot = __builtin_fmaf(ny, v.y, dot);
        dot = __builtin_fmaf(nz, v.z, dot);
        float d2 = (sqmf + sq_b[n]) - 2.0f * dot;
        key[i] = fkey(d2);
      }
      // radix-select rank-95 (byte-wise, 4 passes; same counts/threshold)
      unsigned prefix = 0, pmask = 0;
      int r = 95;
      for (int shift = 24; shift >= 0; shift -= 8) {
        if (t < 256) hist[t] = 0;
        __syncthreads();
#pragma unroll
        for (int i = 0; i < 16; ++i) {
          if ((key[i] & pmask) == prefix)
            atomicAdd(&hist[(key[i] >> shift) & 255], 1u);
        }
        __syncthreads();
        if (t < 16) {
          unsigned ssum = 0;
#pragma unroll
          for (int jj = 0; jj < 16; ++jj) ssum += hist[t * 16 + jj];
          gsum[t] = ssum;
        }
        __syncthreads();
        if (t == 0) {
          int rr = r;
          unsigned g = 0;
          for (unsigned jj = 0; jj < 16; ++jj) {
            int c = (int)gsum[jj];
            if (rr < c) { g = jj; break; }
            rr -= c;
          }
          unsigned bin = g * 16;
          for (unsigned jj = 0; jj < 16; ++jj) {
            int c = (int)hist[g * 16 + jj];
            if (rr < c) { bin = g * 16 + jj; break; }
            rr -= c;
          }
          sh_prefix = prefix | (bin << shift);
          sh_r = rr;
        }
        __syncthreads();
        prefix = sh_prefix;
        r = sh_r;
        pmask |= (0xFFu << shift);
      }
      const unsigned T = prefix;  // collect keys <= T (>=96 candidates; cap 128)
      if (t == 0) cnt = 0;
      __syncthreads();
#pragma unroll
      for (int i = 0; i < 16; ++i) {
        if (key[i] <= T) {
          int pos = atomicAdd(&cnt, 1);
          if (pos < 128) {
            unsigned n = (unsigned)(t + (i << 10));
            karr[pos] = ((unsigned long long)key[i] << 32) | n;
          }
        }
      }
      __syncthreads();
      const int nc = cnt < 128 ? cnt : 128;
      if (t < 128 && t >= nc) karr[t] = ~0ull;
      // 128-wide bitonic sort ascending (identical to standalone version)
      for (int k = 2; k <= 128; k <<= 1) {
        for (int jj = k >> 1; jj > 0; jj >>= 1) {
          __syncthreads();
          if (t < 64) {
            int i = ((t & ~(jj - 1)) << 1) | (t & (jj - 1));
            int ip = i | jj;
            unsigned long long ka = karr[i], kb = karr[ip];
            bool asc = ((i & k) == 0);
            if ((ka > kb) == asc) { karr[i] = kb; karr[ip] = ka; }
          }
        }
      }
      __syncthreads();
      if (t < 32) {
        int ri = rand_idx[t];  // in [0,64)
        sel[bm * 32 + t] = (int)(unsigned)(karr[ri] & 0xFFFFFFFFu);
      }
      __syncthreads();  // protect LDS reuse across items
    }
  }
}

// ---------------- kernel 3: fused group pipeline (nodeidx indirection) ----------------
__global__ __launch_bounds__(256) void group_kernel(
    const float* __restrict__ x, const int* __restrict__ nodeidx,
    const int* __restrict__ sel, const float* __restrict__ w_e1,
    const float* __restrict__ g1, const float* __restrict__ b1,
    const float* __restrict__ w_e2, const float* __restrict__ g2,
    const float* __restrict__ b2, float* __restrict__ out,
    float* __restrict__ gcf) {
#pragma clang fp contract(off)
  const int bm = blockIdx.x;
  const int b = bm >> 9;
  const int m = bm & 511;
  const int t = threadIdx.x;

  __shared__ float cl[32][13];
  __shared__ float h1t[64][36];
  __shared__ float h1p[32][68];
  __shared__ unsigned char nbr[32][8];
  __shared__ double sqs[32];
  __shared__ float part[4][32];
  __shared__ float aws[32];
  __shared__ union U {
    struct {
      unsigned long long keys[32][32];
      float we_a[12][64];
      float we_d[12][64];
      float a1[32][65];
      float cd1[32][65];
    } s;
    float a2[32 * 256];
  } u;

  const float4* xb = (const float4*)(x + (size_t)b * Nn * 4);
  const float4 ndv = xb[nodeidx[bm]];  // same values as before (copy of x row)

  if (t < 32) {
    int n = sel[bm * 32 + t];
    float4 v = xb[n];
    float rx = v.x - ndv.x;
    float ry = v.y - ndv.y;
    float rz = v.z - ndv.z;
    float ds = (rx * rx + ry * ry) + rz * rz;
    ds = __fsqrt_rn(ds);
    cl[t][0] = ndv.x; cl[t][1] = ndv.y; cl[t][2] = ndv.z; cl[t][3] = ndv.w;
    cl[t][4] = v.x;   cl[t][5] = v.y;   cl[t][6] = v.z;   cl[t][7] = v.w;
    cl[t][8] = rx;    cl[t][9] = ry;    cl[t][10] = rz;   cl[t][11] = ds;
  }
  for (int i = t; i < 768; i += 256) {
    int row = i >> 6, d = i & 63;
    float wa = w_e1[row * 64 + d];
    float wb = w_e1[(row + 12) * 64 + d];
    u.s.we_a[row][d] = wa;
    u.s.we_d[row][d] = wb - wa;
  }
  __syncthreads();

  for (int i = t; i < 384; i += 256) {
    int c = i >> 5, p = i & 31;
    out[O_RC + (((size_t)(b * 12 + c) * 512) + m) * 32 + p] = cl[p][c];
  }
  if (t < 32) {
    double q[12];
#pragma unroll
    for (int c = 0; c < 12; ++c) {
      double cv = (double)cl[t][c];
      q[c] = cv * cv;
    }
    double s01 = q[0] + q[1];
    double s23 = q[2] + q[3];
    double s45 = q[4] + q[5];
    double s67 = q[6] + q[7];
    double s = (s01 + s23) + (s45 + s67);
    s = s + q[8];
    s = s + q[9];
    s = s + q[10];
    s = s + q[11];
    sqs[t] = s;
  }
  __syncthreads();

  // pairwise d2 (12-d, fp64 order-exact) -> keys
  {
    int p = t >> 3, q0 = (t & 7) << 2;
#pragma unroll
    for (int qq = 0; qq < 4; ++qq) {
      int q = q0 + qq;
      double dot = 0.0;
#pragma unroll
      for (int c = 0; c < 12; ++c)
        dot = dot + (double)cl[p][c] * (double)cl[q][c];
      double d2 = (sqs[p] + sqs[q]) - 2.0 * dot;
      u.s.keys[p][q] = dkey(d2);
    }
  }
  __syncthreads();

  // parallel rank-select top-8 (identical stable lowest-index-ties semantics)
  {
    int p = t >> 3, s8 = t & 7;
    unsigned long long kq0 = u.s.keys[p][s8];
    unsigned long long kq1 = u.s.keys[p][s8 + 8];
    unsigned long long kq2 = u.s.keys[p][s8 + 16];
    unsigned long long kq3 = u.s.keys[p][s8 + 24];
    int r0 = 0, r1 = 0, r2 = 0, r3 = 0;
#pragma unroll
    for (int j = 0; j < 32; ++j) {
      int jj = (j + p) & 31;  // lane-staggered: conflict-free row reads
      unsigned long long kj = u.s.keys[p][jj];
      r0 += (kj < kq0 || (kj == kq0 && jj < s8));
      r1 += (kj < kq1 || (kj == kq1 && jj < s8 + 8));
      r2 += (kj < kq2 || (kj == kq2 && jj < s8 + 16));
      r3 += (kj < kq3 || (kj == kq3 && jj < s8 + 24));
    }
    if (r0 < 8) nbr[p][r0] = (unsigned char)s8;
    if (r1 < 8) nbr[p][r1] = (unsigned char)(s8 + 8);
    if (r2 < 8) nbr[p][r2] = (unsigned char)(s8 + 16);
    if (r3 < 8) nbr[p][r3] = (unsigned char)(s8 + 24);
  }
  {
    int d = t & 63, pg = (t >> 6) << 3;
#pragma unroll
    for (int pp = 0; pp < 8; ++pp) {
      int p = pg + pp;
      float aA = 0.f, aD = 0.f;
#pragma unroll
      for (int c = 0; c < 12; ++c) {
        float xv = cl[p][c];
        aA = fmaf(xv, u.s.we_a[c][d], aA);
        aD = fmaf(xv, u.s.we_d[c][d], aD);
      }
      u.s.a1[p][d] = aA;
      u.s.cd1[p][d] = aD;
    }
  }
  __syncthreads();

  {
    int d = t & 63, pg = (t >> 6) << 3;
    float g1v = g1[d], b1v = b1[d];
#pragma unroll
    for (int pp = 0; pp < 8; ++pp) {
      int p = pg + pp;
      float cd = u.s.cd1[p][d];
      float hm = -1e30f;
#pragma unroll
      for (int k = 0; k < 8; ++k) {
        int j = nbr[p][k];
        float hv = fmaf(g1v, u.s.a1[j][d] + cd, b1v);
        hv = fmaxf(hv, 0.f);
        hm = fmaxf(hm, hv);
      }
      h1t[d][p] = hm;
      h1p[p][d] = hm;
    }
  }
  __syncthreads();

  if (t < 32) {
    double r[8];
#pragma unroll
    for (int j = 0; j < 8; ++j) {
      double hv = (double)h1p[t][j];
      r[j] = hv * hv;
    }
#pragma unroll
    for (int blk = 1; blk < 8; ++blk) {
#pragma unroll
      for (int j = 0; j < 8; ++j) {
        double hv = (double)h1p[t][blk * 8 + j];
        r[j] = r[j] + hv * hv;
      }
    }
    double s01 = r[0] + r[1];
    double s23 = r[2] + r[3];
    double s45 = r[4] + r[5];
    double s67 = r[6] + r[7];
    sqs[t] = (s01 + s23) + (s45 + s67);
  }
  __syncthreads();

  // pairwise d2 over h1 (64-d, fp64, float4-vectorized; same seq order)
  {
    int p = t >> 3, q0 = (t & 7) << 2;
    const float4* rp = (const float4*)&h1p[p][0];
    for (int qq = 0; qq < 4; ++qq) {
      int q = q0 + qq;
      const float4* rq = (const float4*)&h1p[q][0];
      double dot = 0.0;
#pragma unroll
      for (int c4 = 0; c4 < 16; ++c4) {
        float4 av = rp[c4];
        float4 bv = rq[c4];
        dot = dot + (double)av.x * (double)bv.x;
        dot = dot + (double)av.y * (double)bv.y;
        dot = dot + (double)av.z * (double)bv.z;
        dot = dot + (double)av.w * (double)bv.w;
      }
      double d2 = (sqs[p] + sqs[q]) - 2.0 * dot;
      u.s.keys[p][q] = dkey(d2);
    }
  }
  __syncthreads();

  // parallel rank-select top-8 (second neighbor search)
  {
    int p = t >> 3, s8 = t & 7;
    unsigned long long kq0 = u.s.keys[p][s8];
    unsigned long long kq1 = u.s.keys[p][s8 + 8];
    unsigned long long kq2 = u.s.keys[p][s8 + 16];
    unsigned long long kq3 = u.s.keys[p][s8 + 24];
    int r0 = 0, r1 = 0, r2 = 0, r3 = 0;
#pragma unroll
    for (int j = 0; j < 32; ++j) {
      int jj = (j + p) & 31;
      unsigned long long kj = u.s.keys[p][jj];
      r0 += (kj < kq0 || (kj == kq0 && jj < s8));
      r1 += (kj < kq1 || (kj == kq1 && jj < s8 + 8));
      r2 += (kj < kq2 || (kj == kq2 && jj < s8 + 16));
      r3 += (kj < kq3 || (kj == kq3 && jj < s8 + 24));
    }
    if (r0 < 8) nbr[p][r0] = (unsigned char)s8;
    if (r1 < 8) nbr[p][r1] = (unsigned char)(s8 + 8);
    if (r2 < 8) nbr[p][r2] = (unsigned char)(s8 + 16);
    if (r3 < 8) nbr[p][r3] = (unsigned char)(s8 + 24);
  }
  __syncthreads();

  float accD[32];
  float embv[32];
  {
    float accA[32];
#pragma unroll
    for (int p = 0; p < 32; ++p) { accA[p] = 0.f; accD[p] = 0.f; }
    for (int c = 0; c < 64; ++c) {
      float wt = w_e2[c * 256 + t];
      float wb = w_e2[(c + 64) * 256 + t];
      float wd = wb - wt;
      const float4* row = (const float4*)&h1t[c][0];
#pragma unroll
      for (int p4 = 0; p4 < 8; ++p4) {
        float4 hv = row[p4];
        accA[4 * p4 + 0] = fmaf(hv.x, wt, accA[4 * p4 + 0]);
        accA[4 * p4 + 1] = fmaf(hv.y, wt, accA[4 * p4 + 1]);
        accA[4 * p4 + 2] = fmaf(hv.z, wt, accA[4 * p4 + 2]);
        accA[4 * p4 + 3] = fmaf(hv.w, wt, accA[4 * p4 + 3]);
        accD[4 * p4 + 0] = fmaf(hv.x, wd, accD[4 * p4 + 0]);
        accD[4 * p4 + 1] = fmaf(hv.y, wd, accD[4 * p4 + 1]);
        accD[4 * p4 + 2] = fmaf(hv.z, wd, accD[4 * p4 + 2]);
        accD[4 * p4 + 3] = fmaf(hv.w, wd, accD[4 * p4 + 3]);
      }
    }
#pragma unroll
    for (int p = 0; p < 32; ++p) u.a2[p * 256 + t] = accA[p];
  }
  __syncthreads();
  {
    float g2v = g2[t], b2v = b2[t];
#pragma unroll
    for (int p = 0; p < 32; ++p) {
      float cd = accD[p];
      float e = -1e30f;
#pragma unroll
      for (int k = 0; k < 8; ++k) {
        int j = nbr[p][k];
        float hv = fmaf(g2v, u.a2[j * 256 + t] + cd, b2v);
        hv = fmaxf(hv, 0.f);
        e = fmaxf(e, hv);
      }
      embv[p] = e;
    }
  }

#pragma unroll
  for (int p = 0; p < 32; ++p) {
    float v = embv[p];
#pragma unroll
    for (int off = 32; off > 0; off >>= 1) v = fmaxf(v, __shfl_xor(v, off));
    if ((t & 63) == 0) part[t >> 6][p] = v;
  }
  __syncthreads();

  if (t < 32) {
    float x1 = fmaxf(fmaxf(part[0][t], part[1][t]), fmaxf(part[2][t], part[3][t]));
    float mx = x1;
#pragma unroll
    for (int off = 16; off > 0; off >>= 1) mx = fmaxf(mx, __shfl_xor(mx, off));
    float ex = expf(x1 - mx);
    float sm = ex;
#pragma unroll
    for (int off = 16; off > 0; off >>= 1) sm += __shfl_xor(sm, off);
    float aw = ex / sm;
    aws[t] = aw;
#pragma unroll
    for (int c = 0; c < 3; ++c) {
      float kv = aw * cl[t][4 + c];
#pragma unroll
      for (int off = 16; off > 0; off >>= 1) kv += __shfl_xor(kv, off);
      if (t == 0) out[((size_t)(b * 3 + c)) * 512 + m] = kv;
    }
  }
  __syncthreads();

  {
    float gsum2 = 0.f;
    size_t abase = (size_t)O_AFM + (((size_t)(b * 256 + t)) * 512 + m) * 32;
    float4* ap = (float4*)(out + abase);
#pragma unroll
    for (int p4 = 0; p4 < 8; ++p4) {
      float4 o;
      o.x = embv[4 * p4 + 0] * aws[4 * p4 + 0];
      o.y = embv[4 * p4 + 1] * aws[4 * p4 + 1];
      o.z = embv[4 * p4 + 2] * aws[4 * p4 + 2];
      o.w = embv[4 * p4 + 3] * aws[4 * p4 + 3];
      gsum2 += o.x; gsum2 += o.y; gsum2 += o.z; gsum2 += o.w;
      ap[p4] = o;
    }
    gcf[((size_t)(b * 256 + t)) * 512 + m] = gsum2;
  }
}

// ---------------- kernel 4: MLP head ----------------
__global__ __launch_bounds__(256) void mlp_kernel(
    const float* __restrict__ gcf, const float* __restrict__ w_m1,
    const float* __restrict__ bm1, const float* __restrict__ gm1,
    const float* __restrict__ bbm1, const float* __restrict__ w_m2,
    const float* __restrict__ bm2, const float* __restrict__ gm2,
    const float* __restrict__ bbm2, const float* __restrict__ w_m3,
    const float* __restrict__ bm3, float* __restrict__ out) {
  const int blk = blockIdx.x;
  const int b = blk >> 4;
  const int m0 = (blk & 15) << 5;
  const int t = threadIdx.x;
  __shared__ float sbuf[256 * 36];

#pragma unroll
  for (int i = 0; i < 32; ++i) {
    int c = (t >> 5) + (i << 3);
    int j = t & 31;
    sbuf[c * 36 + j] = gcf[((size_t)(b * 256 + c)) * 512 + m0 + j];
  }
  __syncthreads();

  float acc[32];
#pragma unroll
  for (int j = 0; j < 32; ++j) acc[j] = 0.f;
  for (int c = 0; c < 256; ++c) {
    float wv = w_m1[c * 256 + t];
    const float4* row = (const float4*)&sbuf[c * 36];
#pragma unroll
    for (int j4 = 0; j4 < 8; ++j4) {
      float4 g4 = row[j4];
      acc[4 * j4 + 0] = fmaf(g4.x, wv, acc[4 * j4 + 0]);
      acc[4 * j4 + 1] = fmaf(g4.y, wv, acc[4 * j4 + 1]);
      acc[4 * j4 + 2] = fmaf(g4.z, wv, acc[4 * j4 + 2]);
      acc[4 * j4 + 3] = fmaf(g4.w, wv, acc[4 * j4 + 3]);
    }
  }
  float y[32];
  {
    float gv = gm1[t], bv = bm1[t], bbv = bbm1[t];
#pragma unroll
    for (int j = 0; j < 32; ++j) y[j] = fmaxf(fmaf(gv, acc[j] + bv, bbv), 0.f);
  }
  __syncthreads();
#pragma unroll
  for (int j = 0; j < 32; ++j) sbuf[t * 36 + j] = y[j];
  __syncthreads();

#pragma unroll
  for (int j = 0; j < 32; ++j) acc[j] = 0.f;
  for (int c = 0; c < 256; ++c) {
    float wv = w_m2[c * 256 + t];
    const float4* row = (const float4*)&sbuf[c * 36];
#pragma unroll
    for (int j4 = 0; j4 < 8; ++j4) {
      float4 g4 = row[j4];
      acc[4 * j4 + 0] = fmaf(g4.x, wv, acc[4 * j4 + 0]);
      acc[4 * j4 + 1] = fmaf(g4.y, wv, acc[4 * j4 + 1]);
      acc[4 * j4 + 2] = fmaf(g4.z, wv, acc[4 * j4 + 2]);
      acc[4 * j4 + 3] = fmaf(g4.w, wv, acc[4 * j4 + 3]);
    }
  }
  {
    float gv = gm2[t], bv = bm2[t], bbv = bbm2[t];
#pragma unroll
    for (int j = 0; j < 32; ++j) y[j] = fmaxf(fmaf(gv, acc[j] + bv, bbv), 0.f);
  }
  __syncthreads();
  {
    float w3v = w_m3[t];
#pragma unroll
    for (int j = 0; j < 32; ++j) sbuf[t * 36 + j] = y[j] * w3v;
  }
  __syncthreads();
  if (t < 32) {
    float s = 0.f;
    for (int d = 0; d < 256; ++d) s += sbuf[d * 36 + t];
    s += bm3[0];
    float sal = log1pf(expf(-fabsf(s))) + fmaxf(s, 0.f) + 0.001f;
    out[O_SAL + (size_t)b * 512 + m0 + t] = sal;
  }
}

extern "C" void kernel_launch(void* const* d_in, const int* in_sizes, int n_in,
                              void* d_out, int out_size, void* d_ws, size_t ws_size,
                              hipStream_t stream) {
  (void)in_sizes; (void)n_in; (void)out_size; (void)ws_size;
  const float* x = (const float*)d_in[0];
  const int* rand_idx = (const int*)d_in[1];
  const float* w_e1 = (const float*)d_in[2];
  const float* g1 = (const float*)d_in[3];
  const float* b1 = (const float*)d_in[4];
  const float* w_e2 = (const float*)d_in[5];
  const float* g2 = (const float*)d_in[6];
  const float* b2 = (const float*)d_in[7];
  const float* w_m1 = (const float*)d_in[8];
  const float* bm1 = (const float*)d_in[9];
  const float* gm1 = (const float*)d_in[10];
  const float* bbm1 = (const float*)d_in[11];
  const float* w_m2 = (const float*)d_in[12];
  const float* bm2 = (const float*)d_in[13];
  const float* gm2 = (const float*)d_in[14];
  const float* bbm2 = (const float*)d_in[15];
  const float* w_m3 = (const float*)d_in[16];
  const float* bm3 = (const float*)d_in[17];
  float* out = (float*)d_out;
  char* ws = (char*)d_ws;

  int* nodeidx = (int*)ws;                              // 8 KB used (32 KB region)
  float* sqp = (float*)(ws + 32768);                    // 256 KB
  int* sel = (int*)(ws + 32768 + 262144);               // 256 KB
  float* gcf = (float*)(ws + 32768 + 262144 + 262144);  // 2 MB
  // fps->knn sync flags ALIAS the first 256B of the gcf region (gcf is only
  // written by group_kernel, after the fused kernel; sq zeroes the flags
  // before it). 4 flags, 64B apart. Zero extra workspace bytes.
  unsigned long long* flags = (unsigned long long*)(ws + 32768 + 262144 + 262144);

  sq_kernel<<<256, 256, 0, stream>>>(x, sqp, flags);
  fused_fps_knn<<<256, 1024, 0, stream>>>(x, nodeidx, sqp, rand_idx, sel, flags);
  group_kernel<<<Bn * Mn, 256, 0, stream>>>(x, nodeidx, sel, w_e1, g1, b1, w_e2,
                                            g2, b2, out, gcf);
  mlp_kernel<<<64, 256, 0, stream>>>(gcf, w_m1, bm1, gm1, bbm1, w_m2, bm2, gm2,
                                     bbm2, w_m3, bm3, out);
}

// Round 17
// 1550.099 us; speedup vs baseline: 1.2246x; 1.0489x over previous
//
#include <hip/hip_runtime.h>
#include <cstdint>

#define Bn 4
#define Nn 16384
#define Mn 512
#define Kn 32

// output offsets (floats)
#define O_SAL 6144
#define O_RC  8192
#define O_AFM 794624

__device__ __forceinline__ unsigned fkey(float f) {
  unsigned b = __float_as_uint(f);
  return (b & 0x80000000u) ? ~b : (b | 0x80000000u);
}

__device__ __forceinline__ unsigned long long dkey(double d) {
  unsigned long long b = (unsigned long long)__double_as_longlong(d);
  return (b & 0x8000000000000000ull) ? ~b : (b | 0x8000000000000000ull);
}

// ---- kernel 0: per-point squared norm (np: materialized square + seq sum, NO FMA) ----
__global__ __launch_bounds__(256) void sq_kernel(const float* __restrict__ x,
                                                 float* __restrict__ sqp) {
#pragma clang fp contract(off)
  int i = blockIdx.x * 256 + threadIdx.x;  // < B*N
  float4 v = ((const float4*)x)[i];
  float qx = v.x * v.x;
  float qy = v.y * v.y;
  float qz = v.z * v.z;
  sqp[i] = (qx + qy) + qz;
}

// DPP max step: moved = lane-shuffled v (old = self fallback), then max.
// Values are >= 0 here, so either bound_ctrl semantic (old or 0) is safe.
template <int CTRL>
__device__ __forceinline__ float dppmaxf(float v) {
  int m = __builtin_amdgcn_update_dpp(__float_as_int(v), __float_as_int(v),
                                      CTRL, 0xf, 0xf, false);
  return fmaxf(v, __int_as_float(m));
}

// ---------------- kernel 1: farthest point sampling (fp32, NO contraction) ----------------
// EXACT round-5 version - the best measured fps (884-888us across r5/r9/r11).
// 16-round record: every structural alternative measured worse - packed-math
// r3 894, multiblock+atomics r7 969, LDS-resident r8 985, fused r12-r16
// 1115-1511 (co-tenancy tax > overlap win). This structure's floor is
// ~1.73us/step. Banked as final.
__global__ __launch_bounds__(1024)
__attribute__((amdgpu_waves_per_eu(4, 4)))
void fps_kernel(const float* __restrict__ x, float* __restrict__ node) {
#pragma clang fp contract(off)
  const int b = blockIdx.x;
  const int t = threadIdx.x;
  const float4* xb = (const float4*)(x + (size_t)b * Nn * 4);
  float px[16], py[16], pz[16], mind[16];
  const int base = t * 16;
#pragma unroll
  for (int i = 0; i < 16; ++i) {
    float4 v = xb[base + i];
    px[i] = v.x; py[i] = v.y; pz[i] = v.z;
    mind[i] = 1e10f;
  }
  __shared__ __align__(16) unsigned long long kkey[2][16];
  float cx, cy, cz;
  {
    float4 v = xb[0];
    cx = v.x; cy = v.y; cz = v.z;
    if (t == 0) ((float4*)node)[b * Mn] = v;
  }
  for (int s = 1; s < Mn; ++s) {
    // pass 1: distance + running min (exact np order, no contraction)
#pragma unroll
    for (int i = 0; i < 16; ++i) {
      float dx = px[i] - cx;
      float dy = py[i] - cy;
      float dz = pz[i] - cz;
      float qx = dx * dx;
      float qy = dy * dy;
      float qz = dz * dz;
      float d = (qx + qy) + qz;
      mind[i] = fminf(mind[i], d);
    }
    // pass 2: value max tree (v_max returns an input exactly; no NaN here)
    float a0 = fmaxf(mind[0], mind[1]);
    float a1 = fmaxf(mind[2], mind[3]);
    float a2 = fmaxf(mind[4], mind[5]);
    float a3 = fmaxf(mind[6], mind[7]);
    float a4 = fmaxf(mind[8], mind[9]);
    float a5 = fmaxf(mind[10], mind[11]);
    float a6 = fmaxf(mind[12], mind[13]);
    float a7 = fmaxf(mind[14], mind[15]);
    float b0 = fmaxf(a0, a1);
    float b1 = fmaxf(a2, a3);
    float b2 = fmaxf(a4, a5);
    float b3 = fmaxf(a6, a7);
    float bv = fmaxf(fmaxf(b0, b1), fmaxf(b2, b3));
    // pass 3: lowest matching lane-local index (descending scan)
    int isel = 0;
#pragma unroll
    for (int i = 15; i >= 0; --i)
      if (mind[i] == bv) isel = i;
    // wave reduce: value-only DPP max -> lane 63 -> uniform
    float r = bv;
    r = dppmaxf<0x111>(r);  // row_shr:1
    r = dppmaxf<0x112>(r);  // row_shr:2
    r = dppmaxf<0x114>(r);  // row_shr:4
    r = dppmaxf<0x118>(r);  // row_shr:8
    r = dppmaxf<0x142>(r);  // row_bcast:15
    r = dppmaxf<0x143>(r);  // row_bcast:31
    float wmax = __int_as_float(__builtin_amdgcn_readlane(__float_as_int(r), 63));
    unsigned long long ball = __ballot(bv == wmax);
    int wl = __ffsll(ball) - 1;            // lowest tying lane
    int widx = __builtin_amdgcn_readlane(base + isel, wl);
    if ((t & 63) == 0) {
      kkey[s & 1][t >> 6] =
          ((unsigned long long)(__float_as_uint(wmax) | 0x80000000u) << 32) |
          (unsigned)(~widx);
    }
    __syncthreads();
    {
      // lane-parallel block max: lane reads kkey[t&15] (16 u64 = all 32
      // banks; lanes 16+ broadcast), 4-step xor-net max within 16-lane groups
      unsigned long long kk = kkey[s & 1][t & 15];
#pragma unroll
      for (int off = 1; off < 16; off <<= 1) {
        unsigned long long ok = __shfl_xor(kk, off, 16);
        kk = ok > kk ? ok : kk;
      }
      // uniform across the block -> scalarize the winner reload
      int wi = __builtin_amdgcn_readfirstlane((int)(~(unsigned)(kk & 0xFFFFFFFFu)));
      float4 nv = xb[wi];
      cx = nv.x; cy = nv.y; cz = nv.z;
      if (t == 0) ((float4*)node)[b * Mn + s] = nv;
    }
  }
}

// ------- kernel 2: top-64 kNN. EXACT round-5 version (best total config).
// sq terms NON-FMA; dot = sequential forward FMA; combine unfused. Stable
// lowest-index ties. Byte-wise radix: 4 passes x 256 bins. -------
__global__ __launch_bounds__(256) void knn_kernel(const float* __restrict__ x,
                                                  const float* __restrict__ node,
                                                  const float* __restrict__ sqp,
                                                  const int* __restrict__ rand_idx,
                                                  int* __restrict__ sel) {
#pragma clang fp contract(off)
  const int bm = blockIdx.x;
  const int b = bm >> 9;
  const int t = threadIdx.x;
  const float4* xb = (const float4*)(x + (size_t)b * Nn * 4);
  const float* sq_b = sqp + b * Nn;
  float4 nd = ((const float4*)node)[bm];
  const float nx = nd.x, ny = nd.y, nz = nd.z;
  const float sqmf = (nx * nx + ny * ny) + nz * nz;
  unsigned key[64];
#pragma unroll
  for (int i = 0; i < 64; ++i) {
    int n = t + (i << 8);
    float4 v = xb[n];
    float dot = nx * v.x;
    dot = __builtin_fmaf(ny, v.y, dot);
    dot = __builtin_fmaf(nz, v.z, dot);
    float d2 = (sqmf + sq_b[n]) - 2.0f * dot;
    key[i] = fkey(d2);
  }
  // radix-select the rank-95 (0-indexed) key -> guard-banded superset
  __shared__ unsigned hist[256];
  __shared__ unsigned gsum[16];
  __shared__ unsigned sh_prefix;
  __shared__ int sh_r;
  unsigned prefix = 0, pmask = 0;
  int r = 95;
  for (int shift = 24; shift >= 0; shift -= 8) {
    hist[t] = 0;
    __syncthreads();
#pragma unroll
    for (int i = 0; i < 64; ++i) {
      if ((key[i] & pmask) == prefix) atomicAdd(&hist[(key[i] >> shift) & 255], 1u);
    }
    __syncthreads();
    if (t < 16) {
      unsigned ssum = 0;
#pragma unroll
      for (int j = 0; j < 16; ++j) ssum += hist[t * 16 + j];
      gsum[t] = ssum;
    }
    __syncthreads();
    if (t == 0) {
      int rr = r;
      unsigned g = 0;
      for (unsigned j = 0; j < 16; ++j) {
        int c = (int)gsum[j];
        if (rr < c) { g = j; break; }
        rr -= c;
      }
      unsigned bin = g * 16;
      for (unsigned j = 0; j < 16; ++j) {
        int c = (int)hist[g * 16 + j];
        if (rr < c) { bin = g * 16 + j; break; }
        rr -= c;
      }
      sh_prefix = prefix | (bin << shift);
      sh_r = rr;
    }
    __syncthreads();
    prefix = sh_prefix;
    r = sh_r;
    pmask |= (0xFFu << shift);
  }
  const unsigned T = prefix;  // collect all keys <= T (>=96 candidates; cap 128)
  __shared__ int cnt;
  __shared__ unsigned long long karr[128];
  if (t == 0) cnt = 0;
  __syncthreads();
#pragma unroll
  for (int i = 0; i < 64; ++i) {
    if (key[i] <= T) {
      int pos = atomicAdd(&cnt, 1);
      if (pos < 128) {
        unsigned n = (unsigned)(t + (i << 8));
        // idx in low bits: ascending sort => equal d2 resolved LOWEST index first
        karr[pos] = ((unsigned long long)key[i] << 32) | n;
      }
    }
  }
  __syncthreads();
  const int nc = cnt < 128 ? cnt : 128;
  if (t < 128 && t >= nc) karr[t] = ~0ull;
  // 128-wide bitonic sort ascending
  for (int k = 2; k <= 128; k <<= 1) {
    for (int j = k >> 1; j > 0; j >>= 1) {
      __syncthreads();
      if (t < 64) {
        int i = ((t & ~(j - 1)) << 1) | (t & (j - 1));
        int ip = i | j;
        unsigned long long ka = karr[i], kb = karr[ip];
        bool asc = ((i & k) == 0);
        if ((ka > kb) == asc) { karr[i] = kb; karr[ip] = ka; }
      }
    }
  }
  __syncthreads();
  if (t < 32) {
    int ri = rand_idx[t];  // in [0,64)
    sel[bm * 32 + t] = (int)(unsigned)(karr[ri] & 0xFFFFFFFFu);
  }
}

// ---------------- kernel 3: fused group pipeline (r11 version) ----------------
// Parallel rank-select top-8 (replaces serial topk8; provably identical
// stable lowest-index-ties order) + float4-vectorized 64-d fp64 dot
// (same sequential accumulation order -> bit-identical).
__global__ __launch_bounds__(256) void group_kernel(
    const float* __restrict__ x, const float* __restrict__ node,
    const int* __restrict__ sel, const float* __restrict__ w_e1,
    const float* __restrict__ g1, const float* __restrict__ b1,
    const float* __restrict__ w_e2, const float* __restrict__ g2,
    const float* __restrict__ b2, float* __restrict__ out,
    float* __restrict__ gcf) {
#pragma clang fp contract(off)
  const int bm = blockIdx.x;
  const int b = bm >> 9;
  const int m = bm & 511;
  const int t = threadIdx.x;

  __shared__ float cl[32][13];
  __shared__ float h1t[64][36];
  __shared__ float h1p[32][68];
  __shared__ unsigned char nbr[32][8];
  __shared__ double sqs[32];
  __shared__ float part[4][32];
  __shared__ float aws[32];
  __shared__ union U {
    struct {
      unsigned long long keys[32][32];
      float we_a[12][64];
      float we_d[12][64];
      float a1[32][65];
      float cd1[32][65];
    } s;
    float a2[32 * 256];
  } u;

  const float4* xb = (const float4*)(x + (size_t)b * Nn * 4);
  const float4 ndv = ((const float4*)node)[bm];

  if (t < 32) {
    int n = sel[bm * 32 + t];
    float4 v = xb[n];
    float rx = v.x - ndv.x;
    float ry = v.y - ndv.y;
    float rz = v.z - ndv.z;
    float ds = (rx * rx + ry * ry) + rz * rz;
    ds = __fsqrt_rn(ds);
    cl[t][0] = ndv.x; cl[t][1] = ndv.y; cl[t][2] = ndv.z; cl[t][3] = ndv.w;
    cl[t][4] = v.x;   cl[t][5] = v.y;   cl[t][6] = v.z;   cl[t][7] = v.w;
    cl[t][8] = rx;    cl[t][9] = ry;    cl[t][10] = rz;   cl[t][11] = ds;
  }
  for (int i = t; i < 768; i += 256) {
    int row = i >> 6, d = i & 63;
    float wa = w_e1[row * 64 + d];
    float wb = w_e1[(row + 12) * 64 + d];
    u.s.we_a[row][d] = wa;
    u.s.we_d[row][d] = wb - wa;
  }
  __syncthreads();

  for (int i = t; i < 384; i += 256) {
    int c = i >> 5, p = i & 31;
    out[O_RC + (((size_t)(b * 12 + c) * 512) + m) * 32 + p] = cl[p][c];
  }
  if (t < 32) {
    double q[12];
#pragma unroll
    for (int c = 0; c < 12; ++c) {
      double cv = (double)cl[t][c];
      q[c] = cv * cv;
    }
    double s01 = q[0] + q[1];
    double s23 = q[2] + q[3];
    double s45 = q[4] + q[5];
    double s67 = q[6] + q[7];
    double s = (s01 + s23) + (s45 + s67);
    s = s + q[8];
    s = s + q[9];
    s = s + q[10];
    s = s + q[11];
    sqs[t] = s;
  }
  __syncthreads();

  // pairwise d2 (12-d, fp64 order-exact) -> keys
  {
    int p = t >> 3, q0 = (t & 7) << 2;
#pragma unroll
    for (int qq = 0; qq < 4; ++qq) {
      int q = q0 + qq;
      double dot = 0.0;
#pragma unroll
      for (int c = 0; c < 12; ++c)
        dot = dot + (double)cl[p][c] * (double)cl[q][c];
      double d2 = (sqs[p] + sqs[q]) - 2.0 * dot;
      u.s.keys[p][q] = dkey(d2);
    }
  }
  __syncthreads();

  // parallel rank-select top-8 (identical stable lowest-index-ties semantics)
  {
    int p = t >> 3, s8 = t & 7;
    unsigned long long kq0 = u.s.keys[p][s8];
    unsigned long long kq1 = u.s.keys[p][s8 + 8];
    unsigned long long kq2 = u.s.keys[p][s8 + 16];
    unsigned long long kq3 = u.s.keys[p][s8 + 24];
    int r0 = 0, r1 = 0, r2 = 0, r3 = 0;
#pragma unroll
    for (int j = 0; j < 32; ++j) {
      int jj = (j + p) & 31;  // lane-staggered: conflict-free row reads
      unsigned long long kj = u.s.keys[p][jj];
      r0 += (kj < kq0 || (kj == kq0 && jj < s8));
      r1 += (kj < kq1 || (kj == kq1 && jj < s8 + 8));
      r2 += (kj < kq2 || (kj == kq2 && jj < s8 + 16));
      r3 += (kj < kq3 || (kj == kq3 && jj < s8 + 24));
    }
    if (r0 < 8) nbr[p][r0] = (unsigned char)s8;
    if (r1 < 8) nbr[p][r1] = (unsigned char)(s8 + 8);
    if (r2 < 8) nbr[p][r2] = (unsigned char)(s8 + 16);
    if (r3 < 8) nbr[p][r3] = (unsigned char)(s8 + 24);
  }
  {
    int d = t & 63, pg = (t >> 6) << 3;
#pragma unroll
    for (int pp = 0; pp < 8; ++pp) {
      int p = pg + pp;
      float aA = 0.f, aD = 0.f;
#pragma unroll
      for (int c = 0; c < 12; ++c) {
        float xv = cl[p][c];
        aA = fmaf(xv, u.s.we_a[c][d], aA);
        aD = fmaf(xv, u.s.we_d[c][d], aD);
      }
      u.s.a1[p][d] = aA;
      u.s.cd1[p][d] = aD;
    }
  }
  __syncthreads();

  {
    int d = t & 63, pg = (t >> 6) << 3;
    float g1v = g1[d], b1v = b1[d];
#pragma unroll
    for (int pp = 0; pp < 8; ++pp) {
      int p = pg + pp;
      float cd = u.s.cd1[p][d];
      float hm = -1e30f;
#pragma unroll
      for (int k = 0; k < 8; ++k) {
        int j = nbr[p][k];
        float hv = fmaf(g1v, u.s.a1[j][d] + cd, b1v);
        hv = fmaxf(hv, 0.f);
        hm = fmaxf(hm, hv);
      }
      h1t[d][p] = hm;
      h1p[p][d] = hm;
    }
  }
  __syncthreads();

  if (t < 32) {
    double r[8];
#pragma unroll
    for (int j = 0; j < 8; ++j) {
      double hv = (double)h1p[t][j];
      r[j] = hv * hv;
    }
#pragma unroll
    for (int blk = 1; blk < 8; ++blk) {
#pragma unroll
      for (int j = 0; j < 8; ++j) {
        double hv = (double)h1p[t][blk * 8 + j];
        r[j] = r[j] + hv * hv;
      }
    }
    double s01 = r[0] + r[1];
    double s23 = r[2] + r[3];
    double s45 = r[4] + r[5];
    double s67 = r[6] + r[7];
    sqs[t] = (s01 + s23) + (s45 + s67);
  }
  __syncthreads();

  // pairwise d2 over h1 (64-d, fp64, float4-vectorized; same seq order)
  {
    int p = t >> 3, q0 = (t & 7) << 2;
    const float4* rp = (const float4*)&h1p[p][0];
    for (int qq = 0; qq < 4; ++qq) {
      int q = q0 + qq;
      const float4* rq = (const float4*)&h1p[q][0];
      double dot = 0.0;
#pragma unroll
      for (int c4 = 0; c4 < 16; ++c4) {
        float4 av = rp[c4];
        float4 bv = rq[c4];
        dot = dot + (double)av.x * (double)bv.x;
        dot = dot + (double)av.y * (double)bv.y;
        dot = dot + (double)av.z * (double)bv.z;
        dot = dot + (double)av.w * (double)bv.w;
      }
      double d2 = (sqs[p] + sqs[q]) - 2.0 * dot;
      u.s.keys[p][q] = dkey(d2);
    }
  }
  __syncthreads();

  // parallel rank-select top-8 (second neighbor search)
  {
    int p = t >> 3, s8 = t & 7;
    unsigned long long kq0 = u.s.keys[p][s8];
    unsigned long long kq1 = u.s.keys[p][s8 + 8];
    unsigned long long kq2 = u.s.keys[p][s8 + 16];
    unsigned long long kq3 = u.s.keys[p][s8 + 24];
    int r0 = 0, r1 = 0, r2 = 0, r3 = 0;
#pragma unroll
    for (int j = 0; j < 32; ++j) {
      int jj = (j + p) & 31;
      unsigned long long kj = u.s.keys[p][jj];
      r0 += (kj < kq0 || (kj == kq0 && jj < s8));
      r1 += (kj < kq1 || (kj == kq1 && jj < s8 + 8));
      r2 += (kj < kq2 || (kj == kq2 && jj < s8 + 16));
      r3 += (kj < kq3 || (kj == kq3 && jj < s8 + 24));
    }
    if (r0 < 8) nbr[p][r0] = (unsigned char)s8;
    if (r1 < 8) nbr[p][r1] = (unsigned char)(s8 + 8);
    if (r2 < 8) nbr[p][r2] = (unsigned char)(s8 + 16);
    if (r3 < 8) nbr[p][r3] = (unsigned char)(s8 + 24);
  }
  __syncthreads();

  float accD[32];
  float embv[32];
  {
    float accA[32];
#pragma unroll
    for (int p = 0; p < 32; ++p) { accA[p] = 0.f; accD[p] = 0.f; }
    for (int c = 0; c < 64; ++c) {
      float wt = w_e2[c * 256 + t];
      float wb = w_e2[(c + 64) * 256 + t];
      float wd = wb - wt;
      const float4* row = (const float4*)&h1t[c][0];
#pragma unroll
      for (int p4 = 0; p4 < 8; ++p4) {
        float4 hv = row[p4];
        accA[4 * p4 + 0] = fmaf(hv.x, wt, accA[4 * p4 + 0]);
        accA[4 * p4 + 1] = fmaf(hv.y, wt, accA[4 * p4 + 1]);
        accA[4 * p4 + 2] = fmaf(hv.z, wt, accA[4 * p4 + 2]);
        accA[4 * p4 + 3] = fmaf(hv.w, wt, accA[4 * p4 + 3]);
        accD[4 * p4 + 0] = fmaf(hv.x, wd, accD[4 * p4 + 0]);
        accD[4 * p4 + 1] = fmaf(hv.y, wd, accD[4 * p4 + 1]);
        accD[4 * p4 + 2] = fmaf(hv.z, wd, accD[4 * p4 + 2]);
        accD[4 * p4 + 3] = fmaf(hv.w, wd, accD[4 * p4 + 3]);
      }
    }
#pragma unroll
    for (int p = 0; p < 32; ++p) u.a2[p * 256 + t] = accA[p];
  }
  __syncthreads();
  {
    float g2v = g2[t], b2v = b2[t];
#pragma unroll
    for (int p = 0; p < 32; ++p) {
      float cd = accD[p];
      float e = -1e30f;
#pragma unroll
      for (int k = 0; k < 8; ++k) {
        int j = nbr[p][k];
        float hv = fmaf(g2v, u.a2[j * 256 + t] + cd, b2v);
        hv = fmaxf(hv, 0.f);
        e = fmaxf(e, hv);
      }
      embv[p] = e;
    }
  }

#pragma unroll
  for (int p = 0; p < 32; ++p) {
    float v = embv[p];
#pragma unroll
    for (int off = 32; off > 0; off >>= 1) v = fmaxf(v, __shfl_xor(v, off));
    if ((t & 63) == 0) part[t >> 6][p] = v;
  }
  __syncthreads();

  if (t < 32) {
    float x1 = fmaxf(fmaxf(part[0][t], part[1][t]), fmaxf(part[2][t], part[3][t]));
    float mx = x1;
#pragma unroll
    for (int off = 16; off > 0; off >>= 1) mx = fmaxf(mx, __shfl_xor(mx, off));
    float ex = expf(x1 - mx);
    float sm = ex;
#pragma unroll
    for (int off = 16; off > 0; off >>= 1) sm += __shfl_xor(sm, off);
    float aw = ex / sm;
    aws[t] = aw;
#pragma unroll
    for (int c = 0; c < 3; ++c) {
      float kv = aw * cl[t][4 + c];
#pragma unroll
      for (int off = 16; off > 0; off >>= 1) kv += __shfl_xor(kv, off);
      if (t == 0) out[((size_t)(b * 3 + c)) * 512 + m] = kv;
    }
  }
  __syncthreads();

  {
    float gsum = 0.f;
    size_t abase = (size_t)O_AFM + (((size_t)(b * 256 + t)) * 512 + m) * 32;
    float4* ap = (float4*)(out + abase);
#pragma unroll
    for (int p4 = 0; p4 < 8; ++p4) {
      float4 o;
      o.x = embv[4 * p4 + 0] * aws[4 * p4 + 0];
      o.y = embv[4 * p4 + 1] * aws[4 * p4 + 1];
      o.z = embv[4 * p4 + 2] * aws[4 * p4 + 2];
      o.w = embv[4 * p4 + 3] * aws[4 * p4 + 3];
      gsum += o.x; gsum += o.y; gsum += o.z; gsum += o.w;
      ap[p4] = o;
    }
    gcf[((size_t)(b * 256 + t)) * 512 + m] = gsum;
  }
}

// ---------------- kernel 4: MLP head ----------------
__global__ __launch_bounds__(256) void mlp_kernel(
    const float* __restrict__ gcf, const float* __restrict__ w_m1,
    const float* __restrict__ bm1, const float* __restrict__ gm1,
    const float* __restrict__ bbm1, const float* __restrict__ w_m2,
    const float* __restrict__ bm2, const float* __restrict__ gm2,
    const float* __restrict__ bbm2, const float* __restrict__ w_m3,
    const float* __restrict__ bm3, float* __restrict__ out) {
  const int blk = blockIdx.x;
  const int b = blk >> 4;
  const int m0 = (blk & 15) << 5;
  const int t = threadIdx.x;
  __shared__ float sbuf[256 * 36];

#pragma unroll
  for (int i = 0; i < 32; ++i) {
    int c = (t >> 5) + (i << 3);
    int j = t & 31;
    sbuf[c * 36 + j] = gcf[((size_t)(b * 256 + c)) * 512 + m0 + j];
  }
  __syncthreads();

  float acc[32];
#pragma unroll
  for (int j = 0; j < 32; ++j) acc[j] = 0.f;
  for (int c = 0; c < 256; ++c) {
    float wv = w_m1[c * 256 + t];
    const float4* row = (const float4*)&sbuf[c * 36];
#pragma unroll
    for (int j4 = 0; j4 < 8; ++j4) {
      float4 g4 = row[j4];
      acc[4 * j4 + 0] = fmaf(g4.x, wv, acc[4 * j4 + 0]);
      acc[4 * j4 + 1] = fmaf(g4.y, wv, acc[4 * j4 + 1]);
      acc[4 * j4 + 2] = fmaf(g4.z, wv, acc[4 * j4 + 2]);
      acc[4 * j4 + 3] = fmaf(g4.w, wv, acc[4 * j4 + 3]);
    }
  }
  float y[32];
  {
    float gv = gm1[t], bv = bm1[t], bbv = bbm1[t];
#pragma unroll
    for (int j = 0; j < 32; ++j) y[j] = fmaxf(fmaf(gv, acc[j] + bv, bbv), 0.f);
  }
  __syncthreads();
#pragma unroll
  for (int j = 0; j < 32; ++j) sbuf[t * 36 + j] = y[j];
  __syncthreads();

#pragma unroll
  for (int j = 0; j < 32; ++j) acc[j] = 0.f;
  for (int c = 0; c < 256; ++c) {
    float wv = w_m2[c * 256 + t];
    const float4* row = (const float4*)&sbuf[c * 36];
#pragma unroll
    for (int j4 = 0; j4 < 8; ++j4) {
      float4 g4 = row[j4];
      acc[4 * j4 + 0] = fmaf(g4.x, wv, acc[4 * j4 + 0]);
      acc[4 * j4 + 1] = fmaf(g4.y, wv, acc[4 * j4 + 1]);
      acc[4 * j4 + 2] = fmaf(g4.z, wv, acc[4 * j4 + 2]);
      acc[4 * j4 + 3] = fmaf(g4.w, wv, acc[4 * j4 + 3]);
    }
  }
  {
    float gv = gm2[t], bv = bm2[t], bbv = bbm2[t];
#pragma unroll
    for (int j = 0; j < 32; ++j) y[j] = fmaxf(fmaf(gv, acc[j] + bv, bbv), 0.f);
  }
  __syncthreads();
  {
    float w3v = w_m3[t];
#pragma unroll
    for (int j = 0; j < 32; ++j) sbuf[t * 36 + j] = y[j] * w3v;
  }
  __syncthreads();
  if (t < 32) {
    float s = 0.f;
    for (int d = 0; d < 256; ++d) s += sbuf[d * 36 + t];
    s += bm3[0];
    float sal = log1pf(expf(-fabsf(s))) + fmaxf(s, 0.f) + 0.001f;
    out[O_SAL + (size_t)b * 512 + m0 + t] = sal;
  }
}

extern "C" void kernel_launch(void* const* d_in, const int* in_sizes, int n_in,
                              void* d_out, int out_size, void* d_ws, size_t ws_size,
                              hipStream_t stream) {
  (void)in_sizes; (void)n_in; (void)out_size; (void)ws_size;
  const float* x = (const float*)d_in[0];
  const int* rand_idx = (const int*)d_in[1];
  const float* w_e1 = (const float*)d_in[2];
  const float* g1 = (const float*)d_in[3];
  const float* b1 = (const float*)d_in[4];
  const float* w_e2 = (const float*)d_in[5];
  const float* g2 = (const float*)d_in[6];
  const float* b2 = (const float*)d_in[7];
  const float* w_m1 = (const float*)d_in[8];
  const float* bm1 = (const float*)d_in[9];
  const float* gm1 = (const float*)d_in[10];
  const float* bbm1 = (const float*)d_in[11];
  const float* w_m2 = (const float*)d_in[12];
  const float* bm2 = (const float*)d_in[13];
  const float* gm2 = (const float*)d_in[14];
  const float* bbm2 = (const float*)d_in[15];
  const float* w_m3 = (const float*)d_in[16];
  const float* bm3 = (const float*)d_in[17];
  float* out = (float*)d_out;
  char* ws = (char*)d_ws;

  float* node = (float*)ws;                             // 32 KB
  float* sqp = (float*)(ws + 32768);                    // 256 KB
  int* sel = (int*)(ws + 32768 + 262144);               // 256 KB
  float* gcf = (float*)(ws + 32768 + 262144 + 262144);  // 2 MB

  sq_kernel<<<256, 256, 0, stream>>>(x, sqp);
  fps_kernel<<<Bn, 1024, 0, stream>>>(x, node);
  knn_kernel<<<Bn * Mn, 256, 0, stream>>>(x, node, sqp, rand_idx, sel);
  group_kernel<<<Bn * Mn, 256, 0, stream>>>(x, node, sel, w_e1, g1, b1, w_e2,
                                            g2, b2, out, gcf);
  mlp_kernel<<<64, 256, 0, stream>>>(gcf, w_m1, bm1, gm1, bbm1, w_m2, bm2, gm2,
                                     bbm2, w_m3, bm3, out);
}